// Round 13
// baseline (182.732 us; speedup 1.0000x reference)
//
#include <hip/hip_runtime.h>
#include <hip/hip_bf16.h>
#include <stdint.h>

#define SEQ 2048
#define HID 2048
#define NH 16
#define HD 128
// 1/sqrt(128) * log2(e): softmax runs in exp2 domain
#define QSCALE_L2E 0.1275304429019769f

typedef __attribute__((ext_vector_type(4))) float f32x4;
typedef __attribute__((ext_vector_type(8))) short short8;
typedef __attribute__((ext_vector_type(4))) float f4;
typedef __attribute__((ext_vector_type(4))) unsigned short us4;

__device__ __forceinline__ unsigned short f2bu(float f) {
  union { float f; unsigned int u; } c; c.f = f;
  unsigned int u = c.u + 0x7fffu + ((c.u >> 16) & 1u);  // RNE, finite inputs
  return (unsigned short)(u >> 16);
}

__device__ __forceinline__ unsigned short f2bu_fast(float f) {
  union { float f; unsigned int u; } c; c.f = f;
  return (unsigned short)((c.u + 0x8000u) >> 16);
}

__device__ __forceinline__ float b2f(unsigned short u) {
  union { unsigned int u; float f; } c; c.u = ((unsigned int)u) << 16; return c.f;
}

__device__ __forceinline__ float exp2fast(float x) {
  float r; asm("v_exp_f32 %0, %1" : "=v"(r) : "v"(x)); return r;
}

__device__ __forceinline__ void gload_lds16(const void* g, void* l) {
  __builtin_amdgcn_global_load_lds((const __attribute__((address_space(1))) void*)g,
                                   (__attribute__((address_space(3))) void*)l, 16, 0, 0);
}

#define BAR() __builtin_amdgcn_s_barrier()
#define LGKM0() do { asm volatile("s_waitcnt lgkmcnt(0)" ::: "memory"); __builtin_amdgcn_sched_barrier(0); } while (0)
#define VM6()   do { asm volatile("s_waitcnt vmcnt(6)"   ::: "memory"); __builtin_amdgcn_sched_barrier(0); } while (0)
#define VM4()   do { asm volatile("s_waitcnt vmcnt(4)"   ::: "memory"); __builtin_amdgcn_sched_barrier(0); } while (0)
#define VM0()   do { asm volatile("s_waitcnt vmcnt(0)"   ::: "memory"); __builtin_amdgcn_sched_barrier(0); } while (0)

// ---------------- fp32 -> bf16 convert, 5 equal-size arrays (32B/thread) ----
__global__ __launch_bounds__(256) void cvt_kernel(
    const float* __restrict__ s0, const float* __restrict__ s1,
    const float* __restrict__ s2, const float* __restrict__ s3,
    const float* __restrict__ s4,
    unsigned short* __restrict__ d0, unsigned short* __restrict__ d1,
    unsigned short* __restrict__ d2, unsigned short* __restrict__ d3,
    unsigned short* __restrict__ d4, int n)
{
  const float* s; unsigned short* d;
  switch (blockIdx.y) {
    case 0: s = s0; d = d0; break;
    case 1: s = s1; d = d1; break;
    case 2: s = s2; d = d2; break;
    case 3: s = s3; d = d3; break;
    default: s = s4; d = d4; break;
  }
  const int stride = gridDim.x * blockDim.x;
  for (int i = blockIdx.x * blockDim.x + threadIdx.x; i * 8 < n; i += stride) {
    f4 v0 = *(const f4*)&s[i * 8];
    f4 v1 = *(const f4*)&s[i * 8 + 4];
    short8 o;
    o[0] = (short)f2bu(v0[0]); o[1] = (short)f2bu(v0[1]);
    o[2] = (short)f2bu(v0[2]); o[3] = (short)f2bu(v0[3]);
    o[4] = (short)f2bu(v1[0]); o[5] = (short)f2bu(v1[1]);
    o[6] = (short)f2bu(v1[2]); o[7] = (short)f2bu(v1[3]);
    *(short8*)&d[i * 8] = o;
  }
}

// ---------------- 128x128 bf16 GEMM, m97-style single-buffer ----------------
// R18-verified WIN: BM=BN=128, BK=64, 4 waves (2Mx2N), per-wave 64x64.
// SINGLE 32KB LDS buffer + launch_bounds(256,3) -> 3 blocks/CU (m114
// cross-block MFMA/staging overlap covers the per-tile drain).
template<int MODE>
__global__ __launch_bounds__(256, 3) void gemm97(
    const unsigned short* __restrict__ A,
    const unsigned short* __restrict__ B,
    const float* __restrict__ b0, const float* __restrict__ b1, const float* __restrict__ b2,
    unsigned short* __restrict__ O0, unsigned short* __restrict__ O1, unsigned short* __restrict__ O2,
    float* __restrict__ Of, int M, int N, int K)
{
  extern __shared__ unsigned short lds[];  // A[128*64] @0, B[128*64] @8192 el
  const int tid = threadIdx.x;
  const int lane = tid & 63, w = tid >> 6;
  const int g = lane >> 4, q = lane & 15;
  const int wgM = w >> 1, wgN = w & 1;     // 2M x 2N wave grid
  const long bm = (long)blockIdx.y * 128, bn = (long)blockIdx.x * 128;
  const int NK = K >> 6;

  const int srl = lane >> 3;
  const int scE = ((lane & 7) ^ srl) * 8;
  const int c0 = (g ^ (q & 7)) * 8;
  const int c1 = c0 ^ 32;
  const int aB = (wgM * 64 + q) * 64;
  const int bB = (wgN * 64 + q) * 64;

  f32x4 acc[4][4] = {};
  short8 a[4][2], b[4][2];

#define STAGE(gp, gbase, jj, ldsOff) do {                                     \
    _Pragma("unroll")                                                         \
    for (int c_ = 0; c_ < 4; ++c_) {                                          \
      const long row_ = (c_ * 4 + w) * 8 + srl;                               \
      gload_lds16(&(gp)[((gbase) + row_) * (long)K + (jj) * 64 + scE],        \
                  &lds[(ldsOff) + (c_ * 4 + w) * 512]);                       \
    }                                                                         \
  } while (0)

#define QUADD(n0, n1)                                                         \
  do {                                                                        \
    __builtin_amdgcn_s_setprio(1);                                            \
    _Pragma("unroll")                                                         \
    for (int mi_ = 0; mi_ < 4; ++mi_) {                                       \
      acc[mi_][n0] = __builtin_amdgcn_mfma_f32_16x16x32_bf16(                 \
          a[mi_][0], b[n0][0], acc[mi_][n0], 0, 0, 0);                        \
      acc[mi_][n0] = __builtin_amdgcn_mfma_f32_16x16x32_bf16(                 \
          a[mi_][1], b[n0][1], acc[mi_][n0], 0, 0, 0);                        \
      acc[mi_][n1] = __builtin_amdgcn_mfma_f32_16x16x32_bf16(                 \
          a[mi_][0], b[n1][0], acc[mi_][n1], 0, 0, 0);                        \
      acc[mi_][n1] = __builtin_amdgcn_mfma_f32_16x16x32_bf16(                 \
          a[mi_][1], b[n1][1], acc[mi_][n1], 0, 0, 0);                        \
    }                                                                         \
    __builtin_amdgcn_s_setprio(0);                                            \
  } while (0)

  for (int j = 0; j < NK; ++j) {
    STAGE(A, bm, j, 0);
    STAGE(B, bn, j, 8192);
    VM0();
    BAR();
#pragma unroll
    for (int mi = 0; mi < 4; ++mi) {
      a[mi][0] = *(const short8*)&lds[aB + mi * 1024 + c0];
      a[mi][1] = *(const short8*)&lds[aB + mi * 1024 + c1];
    }
#pragma unroll
    for (int ni = 0; ni < 4; ++ni) {
      b[ni][0] = *(const short8*)&lds[8192 + bB + ni * 1024 + c0];
      b[ni][1] = *(const short8*)&lds[8192 + bB + ni * 1024 + c1];
    }
    QUADD(0, 1);
    QUADD(2, 3);
    BAR();
  }

#pragma unroll
  for (int ni = 0; ni < 4; ++ni) {
    const int col = (int)bn + wgN * 64 + ni * 16 + q;
    float bv;
    if (MODE == 4) {
      const int which = col >> 11, c = col & 2047;
      const float* bp = which == 0 ? b0 : (which == 1 ? b1 : b2);
      bv = bp[c];
    } else {
      bv = b0[col];
    }
#pragma unroll
    for (int mi = 0; mi < 4; ++mi)
#pragma unroll
      for (int r = 0; r < 4; ++r) {
        const long row = bm + wgM * 64 + mi * 16 + 4 * g + r;
        const float v = acc[mi][ni][r] + bv;
        if (MODE == 4) {
          const int which = col >> 11, c = col & 2047, head = c >> 7, d = c & 127;
          if (which == 0)      O0[((long)head * SEQ + row) * HD + d] = f2bu(v * QSCALE_L2E);
          else if (which == 1) O1[((long)head * SEQ + row) * HD + d] = f2bu(v);
          else                 O2[((long)head * HD + d) * SEQ + row] = f2bu(v);
        } else {
          Of[row * (long)N + col] = v;
        }
      }
  }
#undef STAGE
#undef QUADD
}

// ---------------- 64x128 bf16 GEMM  C = A[M,K] * B[N,K]^T + bias ------------
// Kept for out-projection (grid 16x32 = 512 blocks).
template<int MODE>
__global__ __launch_bounds__(256, 2) void gemm128(
    const unsigned short* __restrict__ A,
    const unsigned short* __restrict__ B,
    const float* __restrict__ b0, const float* __restrict__ b1, const float* __restrict__ b2,
    unsigned short* __restrict__ O0, unsigned short* __restrict__ O1, unsigned short* __restrict__ O2,
    float* __restrict__ Of, int M, int N, int K)
{
  constexpr int ASZ = 64 * 64;
  constexpr int BSZ = 128 * 64;

  extern __shared__ unsigned short lds[];
  const int tid = threadIdx.x;
  const int lane = tid & 63, w = tid >> 6;
  const int g = lane >> 4, q = lane & 15;
  const long bm = (long)blockIdx.y * 64, bn = (long)blockIdx.x * 128;
  const int NK = K >> 6;

  const int srl = lane >> 3;
  const int scE = ((lane & 7) ^ srl) * 8;
  const int c0 = (g ^ (q & 7)) * 8;
  const int c1 = c0 ^ 32;
  const int aB = q * 64;
  const int bB = (w * 32 + q) * 64;

  f32x4 acc[4][2] = {};
  short8 a[4][2], b[2][2];

#define STAGE_A(jj) do {                                                      \
    unsigned short* dst_ = lds + (((jj) & 1) ? ASZ : 0);                      \
    _Pragma("unroll")                                                         \
    for (int c_ = 0; c_ < 2; ++c_) {                                          \
      const long row_ = (c_ * 4 + w) * 8 + srl;                               \
      gload_lds16(&A[(bm + row_) * (long)K + (jj) * 64 + scE],                \
                  &dst_[(c_ * 4 + w) * 512]);                                 \
    }                                                                         \
  } while (0)

#define STAGE_B(jj) do {                                                      \
    unsigned short* dst_ = lds + 2 * ASZ + (((jj) & 1) ? BSZ : 0);            \
    _Pragma("unroll")                                                         \
    for (int c_ = 0; c_ < 4; ++c_) {                                          \
      const long row_ = (c_ * 4 + w) * 8 + srl;                               \
      gload_lds16(&B[(bn + row_) * (long)K + (jj) * 64 + scE],                \
                  &dst_[(c_ * 4 + w) * 512]);                                 \
    }                                                                         \
  } while (0)

#define QUAD8(ni)                                                             \
  do {                                                                        \
    __builtin_amdgcn_s_setprio(1);                                            \
    _Pragma("unroll")                                                         \
    for (int mi_ = 0; mi_ < 4; ++mi_) {                                       \
      acc[mi_][ni] = __builtin_amdgcn_mfma_f32_16x16x32_bf16(                 \
          a[mi_][0], b[ni][0], acc[mi_][ni], 0, 0, 0);                        \
      acc[mi_][ni] = __builtin_amdgcn_mfma_f32_16x16x32_bf16(                 \
          a[mi_][1], b[ni][1], acc[mi_][ni], 0, 0, 0);                        \
    }                                                                         \
    __builtin_amdgcn_s_setprio(0);                                            \
  } while (0)

  STAGE_A(0); STAGE_B(0);
  STAGE_A(1); STAGE_B(1);
  VM6();
  BAR();

  for (int j = 0; j < NK; ++j) {
    unsigned short* At = lds + ((j & 1) ? ASZ : 0);
    unsigned short* Bt = lds + 2 * ASZ + ((j & 1) ? BSZ : 0);

#pragma unroll
    for (int mi = 0; mi < 4; ++mi) {
      a[mi][0] = *(const short8*)&At[aB + mi * 1024 + c0];
      a[mi][1] = *(const short8*)&At[aB + mi * 1024 + c1];
    }
#pragma unroll
    for (int ni = 0; ni < 2; ++ni) {
      b[ni][0] = *(const short8*)&Bt[bB + ni * 1024 + c0];
      b[ni][1] = *(const short8*)&Bt[bB + ni * 1024 + c1];
    }
    QUAD8(0);
    LGKM0();
    BAR();                                  // (a)
    if (j + 2 < NK) { STAGE_A(j + 2); STAGE_B(j + 2); }
    QUAD8(1);
    if (j < NK - 2) { VM6(); } else { VM0(); }
    BAR();                                  // (b)
  }

#pragma unroll
  for (int ni = 0; ni < 2; ++ni) {
    const int col = (int)bn + w * 32 + ni * 16 + q;
    float bv;
    if (MODE == 4) {
      const int which = col >> 11, c = col & 2047;
      const float* bp = which == 0 ? b0 : (which == 1 ? b1 : b2);
      bv = bp[c];
    } else {
      bv = b0[col];
    }
#pragma unroll
    for (int mi = 0; mi < 4; ++mi)
#pragma unroll
      for (int r = 0; r < 4; ++r) {
        const long row = bm + mi * 16 + 4 * g + r;
        const float v = acc[mi][ni][r] + bv;
        if (MODE == 4) {
          const int which = col >> 11, c = col & 2047, head = c >> 7, d = c & 127;
          if (which == 0)      O0[((long)head * SEQ + row) * HD + d] = f2bu(v * QSCALE_L2E);
          else if (which == 1) O1[((long)head * SEQ + row) * HD + d] = f2bu(v);
          else                 O2[((long)head * HD + d) * SEQ + row] = f2bu(v);
        } else {
          Of[row * (long)N + col] = v;
        }
      }
  }
#undef STAGE_A
#undef STAGE_B
#undef QUAD8
}

// ---------------- flash attention v17: role-split waves ----------------------
// R27: flash was ~100% LDS-read-pipe-bound (per CU-phase: 8 waves x 34 b128
// x 12cy + writes + conflicts ~= the measured 4544 cy). Fix: waves share
// operand reads. Wave w now computes QK^T for ALL 64 q-rows x ITS 16-kv
// quarter (kf: 4 reads, reused across 4 q-blocks; qf[4][4] preloaded in
// regs), writes its P-quarter to a SHARED Pt[64q][64kv] (conflict-free
// write footprint), then after lgkm+barrier computes PV for ALL 64 q x
// ITS 32 d-columns (vf: 4 reads reused; pf: 8). Per-wave b128: 34 -> 16.
// No O-combine needed (d-split epilogue); lsum via per-lane kv-column
// partials + end shfl/LDS reduce. All fragment mappings are the proven
// 16x16x32 ones (A: m=l&15,k=g*8+j; B: n=l&15; D: col=l&15,row=4g+reg).
// Pipeline/staging/dbuf/vmcnt = R26 verbatim.
#define KVB 64
__global__ __launch_bounds__(256) void flash_attn(
    const unsigned short* __restrict__ Qb,
    const unsigned short* __restrict__ Kb,
    const unsigned short* __restrict__ VTb,
    unsigned short* __restrict__ attnb)      // [SEQ][HID] bf16
{
  // S (elements): Kt0 @0 | Kt1 @8192 | Vt0 @16384 | Vt1 @24576 | Pt @32768
  extern __shared__ unsigned short S[];      // 36864 us = 72KB
  const int tid = threadIdx.x;
  const int l = tid & 63, w = tid >> 6;
  const int g = l >> 4, q = l & 15;
  const int bid = blockIdx.x;
  const int jj = bid >> 3;
  const int h = ((bid & 7) << 1) | (jj >> 5);   // 2 heads per XCD (R19-proven)
  const int qbk = jj & 31;
  const long qbase = (long)qbk * 64;

  unsigned short* Pt = S + 32768;            // [64 q][64 kv], blk ^ (row&7)

  // qf[qk][dc]: A-frag rows qbase+qk*16+(l&15), k = g*8+j of d-chunk dc*32
  short8 qf[4][4];
#pragma unroll
  for (int qk = 0; qk < 4; ++qk)
#pragma unroll
    for (int dc = 0; dc < 4; ++dc)
      qf[qk][dc] = *(const short8*)&Qb[((long)h * SEQ + qbase + qk * 16 + q) * HD + dc * 32 + g * 8];

  f32x4 oacc[4][2] = {};                     // [qk][dtl]; D col=d=(2w+dtl)*16+q
  f32x4 saccA[4], saccB[4];                  // [qk]; D col=kv=w*16+q, row=4g+reg
  const f32x4 zero4 = {};
  float plsum[4][4] = {};                    // [qk][r]: per-lane kv-col partials

  const unsigned short* Kg = Kb + (long)h * SEQ * HD;
  const unsigned short* Vg = VTb + (long)h * HD * SEQ;

  // R24-proven staging geometry (pre-swizzled global source, linear LDS dest)
  const int kce = ((l & 15) ^ (l >> 4)) * 8;
  const int kco = kce ^ 32;
  const int vce = ((l & 7) ^ ((l >> 3) & 7)) * 8;
  const int krl = l >> 4;
  const int vrl = l >> 3;
  unsigned short* KdB = S + w * 2048;
  unsigned short* VdB = S + 16384 + w * 2048;

#define STAGE_K(kb_, bufsel) do {                                             \
    const unsigned short* Kp_ = Kg + (long)((kb_) + w * 16 + krl) * HD;       \
    unsigned short* Kd_ = KdB + (bufsel) * 8192;                              \
    gload_lds16(Kp_ + 0 * 4 * HD + kce, Kd_ + 0 * 512);                       \
    gload_lds16(Kp_ + 1 * 4 * HD + kco, Kd_ + 1 * 512);                       \
    gload_lds16(Kp_ + 2 * 4 * HD + kce, Kd_ + 2 * 512);                       \
    gload_lds16(Kp_ + 3 * 4 * HD + kco, Kd_ + 3 * 512);                       \
  } while (0)

#define STAGE_V(kb_, bufsel) do {                                             \
    const unsigned short* Vp_ = Vg + (long)(w * 32 + vrl) * SEQ + (kb_) + vce;\
    unsigned short* Vd_ = VdB + (bufsel) * 8192;                              \
    gload_lds16(Vp_ + 0 * 8 * SEQ, Vd_ + 0 * 512);                            \
    gload_lds16(Vp_ + 1 * 8 * SEQ, Vd_ + 1 * 512);                            \
    gload_lds16(Vp_ + 2 * 8 * SEQ, Vd_ + 2 * 512);                            \
    gload_lds16(Vp_ + 3 * 8 * SEQ, Vd_ + 3 * 512);                            \
  } while (0)

  // QK^T for tile T1: 4 kf reads (this wave's kv quarter), 16 MFMA.
  // kf B-frag: n = l&15 = kv-local (krow = w*16+q), k = g*8+j over d.
#define QKT(T1, SN) do {                                                      \
    const unsigned short* Kt_ = S + ((T1) & 1) * 8192;                        \
    const int krow_ = w * 16 + q;                                             \
    const int ksw_ = (q & 7) << 4;                                            \
    __builtin_amdgcn_s_setprio(1);                                            \
    _Pragma("unroll")                                                         \
    for (int dc = 0; dc < 4; ++dc) {                                          \
      short8 kf_ = *(const short8*)&Kt_[((krow_ * 256 + dc * 64 + g * 16) ^ ksw_) >> 1]; \
      _Pragma("unroll")                                                       \
      for (int qk = 0; qk < 4; ++qk)                                          \
        SN[qk] = __builtin_amdgcn_mfma_f32_16x16x32_bf16(qf[qk][dc], kf_, SN[qk], 0, 0, 0); \
    }                                                                         \
    __builtin_amdgcn_s_setprio(0);                                            \
  } while (0)

  // exp + plsum + shared-Pt write of this wave's kv quarter.
  // sacc D: row = qk*16 + 4g + reg (q), col = l&15 -> kv = w*16 + q.
#define SOFT(SC) do {                                                         \
    _Pragma("unroll")                                                         \
    for (int qk = 0; qk < 4; ++qk)                                            \
      _Pragma("unroll")                                                       \
      for (int r = 0; r < 4; ++r) {                                           \
        const float p_ = exp2fast(SC[qk][r]);                                 \
        plsum[qk][r] += p_;                                                   \
        const int qrow_ = qk * 16 + 4 * g + r;                                \
        Pt[((qrow_ * 128 + (w * 16 + q) * 2) ^ ((qrow_ & 7) << 4)) >> 1] = f2bu_fast(p_); \
      }                                                                       \
  } while (0)

  // PV for tile T: all 64 q x this wave's d-columns (2w,2w+1)*16.
  // vf[dtl][ks]: 4 reads reused across qk; pf: 8 reads; 16 MFMA.
#define PVPART(T) do {                                                        \
    const unsigned short* Vt_ = S + 16384 + ((T) & 1) * 8192;                 \
    const int psw_ = (q & 7) << 4;                                            \
    short8 vfv_[2][2];                                                        \
    _Pragma("unroll")                                                         \
    for (int dtl = 0; dtl < 2; ++dtl) {                                       \
      const int vrow_ = (2 * w + dtl) * 16 + q;                               \
      vfv_[dtl][0] = *(const short8*)&Vt_[((vrow_ * 128 + 0 * 64 + g * 16) ^ psw_) >> 1]; \
      vfv_[dtl][1] = *(const short8*)&Vt_[((vrow_ * 128 + 1 * 64 + g * 16) ^ psw_) >> 1]; \
    }                                                                         \
    __builtin_amdgcn_s_setprio(1);                                            \
    _Pragma("unroll")                                                         \
    for (int qk = 0; qk < 4; ++qk) {                                          \
      const int prow_ = qk * 16 + q;                                          \
      short8 pf0_ = *(const short8*)&Pt[((prow_ * 128 + 0 * 64 + g * 16) ^ psw_) >> 1]; \
      short8 pf1_ = *(const short8*)&Pt[((prow_ * 128 + 1 * 64 + g * 16) ^ psw_) >> 1]; \
      _Pragma("unroll")                                                       \
      for (int dtl = 0; dtl < 2; ++dtl) {                                     \
        oacc[qk][dtl] = __builtin_amdgcn_mfma_f32_16x16x32_bf16(pf0_, vfv_[dtl][0], oacc[qk][dtl], 0, 0, 0); \
        oacc[qk][dtl] = __builtin_amdgcn_mfma_f32_16x16x32_bf16(pf1_, vfv_[dtl][1], oacc[qk][dtl], 0, 0, 0); \
      }                                                                       \
    }                                                                         \
    __builtin_amdgcn_s_setprio(0);                                            \
  } while (0)

#define PHASE(T, SC, SN) do {                                                 \
    if ((T) + 2 < 32) STAGE_K(((T) + 2) * KVB, (T) & 1);                      \
    if ((T) + 1 < 32) {                                                       \
      _Pragma("unroll")                                                       \
      for (int qk_ = 0; qk_ < 4; ++qk_) SN[qk_] = zero4;                      \
      QKT((T) + 1, SN);                                                       \
    }                                                                         \
    SOFT(SC);                                                                 \
    LGKM0();                                                                  \
    BAR();                                  /* alpha: all P(T) visible */     \
    PVPART(T);                                                                \
    BAR();                                  /* beta: Vbuf[T&1]+Pt free */     \
    if ((T) + 2 < 32) STAGE_V(((T) + 2) * KVB, (T) & 1);                      \
    if ((T) <= 29) { VM4(); } else { VM0(); }                                 \
    BAR();                                  /* gamma: staged K visible */     \
  } while (0)

  // ---- prologue: tiles 0,1 staged; QK(0); barrier before PHASE(0)'s
  // STAGE_K(2) overwrite of Kbuf0.
  STAGE_K(0, 0); STAGE_V(0, 0);
  STAGE_K(KVB, 1); STAGE_V(KVB, 1);
  VM0();
  BAR();
#pragma unroll
  for (int qk = 0; qk < 4; ++qk) saccA[qk] = zero4;
  QKT(0, saccA);
  BAR();

  for (int t = 0; t < 32; t += 2) {
    PHASE(t, saccA, saccB);
    PHASE(t + 1, saccB, saccA);
  }

  // ---- epilogue ----
  // reduce plsum over the 16 kv-lanes (l&15) of this wave's quarter
#pragma unroll
  for (int qk = 0; qk < 4; ++qk)
#pragma unroll
    for (int r = 0; r < 4; ++r)
#pragma unroll
      for (int off = 1; off < 16; off <<= 1)
        plsum[qk][r] += __shfl_xor(plsum[qk][r], off);

  __syncthreads();                           // loop done; Pt region dead
  float* Ls2 = (float*)(S + 32768);          // [64 q][4 w] f32 = 1KB
  if (q == 0) {
#pragma unroll
    for (int qk = 0; qk < 4; ++qk)
#pragma unroll
      for (int r = 0; r < 4; ++r)
        Ls2[(qk * 16 + 4 * g + r) * 4 + w] = plsum[qk][r];
  }
  __syncthreads();

#pragma unroll
  for (int qk = 0; qk < 4; ++qk)
#pragma unroll
    for (int r = 0; r < 4; ++r) {
      const int qrow = qk * 16 + 4 * g + r;
      f4 lv = *(const f4*)&Ls2[qrow * 4];
      const float rl = 1.f / ((lv[0] + lv[1]) + (lv[2] + lv[3]));
      const long gbase = (qbase + qrow) * (long)HID + (long)h * HD;
      attnb[gbase + (2 * w + 0) * 16 + q] = f2bu(oacc[qk][0][r] * rl);
      attnb[gbase + (2 * w + 1) * 16 + q] = f2bu(oacc[qk][1][r] * rl);
    }
#undef STAGE_K
#undef STAGE_V
#undef QKT
#undef SOFT
#undef PVPART
#undef PHASE
}

extern "C" void kernel_launch(void* const* d_in, const int* in_sizes, int n_in,
                              void* d_out, int out_size, void* d_ws, size_t ws_size,
                              hipStream_t stream)
{
  const float* x  = (const float*)d_in[0];
  const float* wq = (const float*)d_in[1];
  const float* bq = (const float*)d_in[2];
  const float* wk = (const float*)d_in[3];
  const float* bk = (const float*)d_in[4];
  const float* wv = (const float*)d_in[5];
  const float* bv = (const float*)d_in[6];
  const float* wo = (const float*)d_in[7];
  const float* bo = (const float*)d_in[8];

  const long NEL = (long)HID * HID;
  unsigned short* Xb   = (unsigned short*)d_ws;
  unsigned short* Wqkv = Xb + NEL;
  unsigned short* Wob  = Wqkv + 3 * NEL;
  unsigned short* Qbuf = Wob + NEL;
  unsigned short* Kbuf = Qbuf + NEL;
  unsigned short* VTb  = Kbuf + NEL;
  unsigned short* Attn = VTb + NEL;

  // one-time opt-in for 72KB dynamic LDS (host-side, graph-capture safe)
  static bool attrDone = false;
  if (!attrDone) {
    hipFuncSetAttribute(reinterpret_cast<const void*>(flash_attn),
                        hipFuncAttributeMaxDynamicSharedMemorySize, 73728);
    attrDone = true;
  }

  cvt_kernel<<<dim3(512, 5), 256, 0, stream>>>(
      x, wq, wk, wv, wo, Xb, Wqkv, Wqkv + NEL, Wqkv + 2 * NEL, Wob, (int)NEL);

  gemm97<4><<<dim3(48, 16), 256, 32768, stream>>>(
      Xb, Wqkv, bq, bk, bv, Qbuf, Kbuf, VTb, nullptr, SEQ, 3 * HID, HID);

  flash_attn<<<dim3(512), 256, 73728, stream>>>(Qbuf, Kbuf, VTb, Attn);

  gemm128<3><<<dim3(16, 32), 256, 49152, stream>>>(
      Attn, Wob, bo, nullptr, nullptr, nullptr, nullptr, nullptr,
      (float*)d_out, SEQ, HID, HID);
}

// Round 14
// 168.958 us; speedup vs baseline: 1.0815x; 1.0815x over previous
//
#include <hip/hip_runtime.h>
#include <hip/hip_bf16.h>
#include <stdint.h>

#define SEQ 2048
#define HID 2048
#define NH 16
#define HD 128
// 1/sqrt(128) * log2(e): softmax runs in exp2 domain
#define QSCALE_L2E 0.1275304429019769f

typedef __attribute__((ext_vector_type(4))) float f32x4;
typedef __attribute__((ext_vector_type(8))) short short8;
typedef __attribute__((ext_vector_type(4))) float f4;
typedef __attribute__((ext_vector_type(4))) unsigned short us4;

__device__ __forceinline__ unsigned short f2bu(float f) {
  union { float f; unsigned int u; } c; c.f = f;
  unsigned int u = c.u + 0x7fffu + ((c.u >> 16) & 1u);  // RNE, finite inputs
  return (unsigned short)(u >> 16);
}

__device__ __forceinline__ unsigned short f2bu_fast(float f) {
  union { float f; unsigned int u; } c; c.f = f;
  return (unsigned short)((c.u + 0x8000u) >> 16);
}

__device__ __forceinline__ float b2f(unsigned short u) {
  union { unsigned int u; float f; } c; c.u = ((unsigned int)u) << 16; return c.f;
}

__device__ __forceinline__ float exp2fast(float x) {
  float r; asm("v_exp_f32 %0, %1" : "=v"(r) : "v"(x)); return r;
}

__device__ __forceinline__ void gload_lds16(const void* g, void* l) {
  __builtin_amdgcn_global_load_lds((const __attribute__((address_space(1))) void*)g,
                                   (__attribute__((address_space(3))) void*)l, 16, 0, 0);
}

#define BAR() __builtin_amdgcn_s_barrier()
#define LGKM0() do { asm volatile("s_waitcnt lgkmcnt(0)" ::: "memory"); __builtin_amdgcn_sched_barrier(0); } while (0)
#define VM6()   do { asm volatile("s_waitcnt vmcnt(6)"   ::: "memory"); __builtin_amdgcn_sched_barrier(0); } while (0)
#define VM4()   do { asm volatile("s_waitcnt vmcnt(4)"   ::: "memory"); __builtin_amdgcn_sched_barrier(0); } while (0)
#define VM0()   do { asm volatile("s_waitcnt vmcnt(0)"   ::: "memory"); __builtin_amdgcn_sched_barrier(0); } while (0)

// ---------------- fp32 -> bf16 convert, 5 equal-size arrays (32B/thread) ----
__global__ __launch_bounds__(256) void cvt_kernel(
    const float* __restrict__ s0, const float* __restrict__ s1,
    const float* __restrict__ s2, const float* __restrict__ s3,
    const float* __restrict__ s4,
    unsigned short* __restrict__ d0, unsigned short* __restrict__ d1,
    unsigned short* __restrict__ d2, unsigned short* __restrict__ d3,
    unsigned short* __restrict__ d4, int n)
{
  const float* s; unsigned short* d;
  switch (blockIdx.y) {
    case 0: s = s0; d = d0; break;
    case 1: s = s1; d = d1; break;
    case 2: s = s2; d = d2; break;
    case 3: s = s3; d = d3; break;
    default: s = s4; d = d4; break;
  }
  const int stride = gridDim.x * blockDim.x;
  for (int i = blockIdx.x * blockDim.x + threadIdx.x; i * 8 < n; i += stride) {
    f4 v0 = *(const f4*)&s[i * 8];
    f4 v1 = *(const f4*)&s[i * 8 + 4];
    short8 o;
    o[0] = (short)f2bu(v0[0]); o[1] = (short)f2bu(v0[1]);
    o[2] = (short)f2bu(v0[2]); o[3] = (short)f2bu(v0[3]);
    o[4] = (short)f2bu(v1[0]); o[5] = (short)f2bu(v1[1]);
    o[6] = (short)f2bu(v1[2]); o[7] = (short)f2bu(v1[3]);
    *(short8*)&d[i * 8] = o;
  }
}

// ---------------- 128x128 bf16 GEMM, m97-style single-buffer ----------------
// R18-verified WIN: BM=BN=128, BK=64, 4 waves (2Mx2N), per-wave 64x64.
// SINGLE 32KB LDS buffer + launch_bounds(256,3) -> 3 blocks/CU (m114
// cross-block MFMA/staging overlap covers the per-tile drain).
template<int MODE>
__global__ __launch_bounds__(256, 3) void gemm97(
    const unsigned short* __restrict__ A,
    const unsigned short* __restrict__ B,
    const float* __restrict__ b0, const float* __restrict__ b1, const float* __restrict__ b2,
    unsigned short* __restrict__ O0, unsigned short* __restrict__ O1, unsigned short* __restrict__ O2,
    float* __restrict__ Of, int M, int N, int K)
{
  extern __shared__ unsigned short lds[];  // A[128*64] @0, B[128*64] @8192 el
  const int tid = threadIdx.x;
  const int lane = tid & 63, w = tid >> 6;
  const int g = lane >> 4, q = lane & 15;
  const int wgM = w >> 1, wgN = w & 1;     // 2M x 2N wave grid
  const long bm = (long)blockIdx.y * 128, bn = (long)blockIdx.x * 128;
  const int NK = K >> 6;

  const int srl = lane >> 3;
  const int scE = ((lane & 7) ^ srl) * 8;
  const int c0 = (g ^ (q & 7)) * 8;
  const int c1 = c0 ^ 32;
  const int aB = (wgM * 64 + q) * 64;
  const int bB = (wgN * 64 + q) * 64;

  f32x4 acc[4][4] = {};
  short8 a[4][2], b[4][2];

#define STAGE(gp, gbase, jj, ldsOff) do {                                     \
    _Pragma("unroll")                                                         \
    for (int c_ = 0; c_ < 4; ++c_) {                                          \
      const long row_ = (c_ * 4 + w) * 8 + srl;                               \
      gload_lds16(&(gp)[((gbase) + row_) * (long)K + (jj) * 64 + scE],        \
                  &lds[(ldsOff) + (c_ * 4 + w) * 512]);                       \
    }                                                                         \
  } while (0)

#define QUADD(n0, n1)                                                         \
  do {                                                                        \
    __builtin_amdgcn_s_setprio(1);                                            \
    _Pragma("unroll")                                                         \
    for (int mi_ = 0; mi_ < 4; ++mi_) {                                       \
      acc[mi_][n0] = __builtin_amdgcn_mfma_f32_16x16x32_bf16(                 \
          a[mi_][0], b[n0][0], acc[mi_][n0], 0, 0, 0);                        \
      acc[mi_][n0] = __builtin_amdgcn_mfma_f32_16x16x32_bf16(                 \
          a[mi_][1], b[n0][1], acc[mi_][n0], 0, 0, 0);                        \
      acc[mi_][n1] = __builtin_amdgcn_mfma_f32_16x16x32_bf16(                 \
          a[mi_][0], b[n1][0], acc[mi_][n1], 0, 0, 0);                        \
      acc[mi_][n1] = __builtin_amdgcn_mfma_f32_16x16x32_bf16(                 \
          a[mi_][1], b[n1][1], acc[mi_][n1], 0, 0, 0);                        \
    }                                                                         \
    __builtin_amdgcn_s_setprio(0);                                            \
  } while (0)

  for (int j = 0; j < NK; ++j) {
    STAGE(A, bm, j, 0);
    STAGE(B, bn, j, 8192);
    VM0();                                  // tile landed
    BAR();                                  // all waves see full tile
#pragma unroll
    for (int mi = 0; mi < 4; ++mi) {
      a[mi][0] = *(const short8*)&lds[aB + mi * 1024 + c0];
      a[mi][1] = *(const short8*)&lds[aB + mi * 1024 + c1];
    }
#pragma unroll
    for (int ni = 0; ni < 4; ++ni) {
      b[ni][0] = *(const short8*)&lds[8192 + bB + ni * 1024 + c0];
      b[ni][1] = *(const short8*)&lds[8192 + bB + ni * 1024 + c1];
    }
    QUADD(0, 1);
    QUADD(2, 3);
    BAR();                                  // all reads done -> safe to restage
  }

#pragma unroll
  for (int ni = 0; ni < 4; ++ni) {
    const int col = (int)bn + wgN * 64 + ni * 16 + q;
    float bv;
    if (MODE == 4) {
      const int which = col >> 11, c = col & 2047;
      const float* bp = which == 0 ? b0 : (which == 1 ? b1 : b2);
      bv = bp[c];
    } else {
      bv = b0[col];
    }
#pragma unroll
    for (int mi = 0; mi < 4; ++mi)
#pragma unroll
      for (int r = 0; r < 4; ++r) {
        const long row = bm + wgM * 64 + mi * 16 + 4 * g + r;
        const float v = acc[mi][ni][r] + bv;
        if (MODE == 4) {
          const int which = col >> 11, c = col & 2047, head = c >> 7, d = c & 127;
          if (which == 0)      O0[((long)head * SEQ + row) * HD + d] = f2bu(v * QSCALE_L2E);
          else if (which == 1) O1[((long)head * SEQ + row) * HD + d] = f2bu(v);
          else                 O2[((long)head * HD + d) * SEQ + row] = f2bu(v);
        } else {
          Of[row * (long)N + col] = v;
        }
      }
  }
#undef STAGE
#undef QUADD
}

// ---------------- 64x128 bf16 GEMM, m97-style single-buffer (out-proj) ------
// R28: out-projection ported from the dbuf 2-barrier gemm128 to the gemm97
// loop structure (R18's 1.5x winner on QKV), at the same 64x128 tile:
// single 24KB LDS buffer (A 8KB @0, B 16KB @4096 el), 4 waves (1Mx4N,
// per-wave 64x32, acc[4][2]), loop = STAGE -> VM0 -> BAR -> 12 ds_read ->
// 16 MFMA -> BAR. Grid 16x32 = 512 blocks (2/CU). Reads/epilogue geometry
// verbatim from the proven gemm128.
__global__ __launch_bounds__(256, 3) void gemm97o(
    const unsigned short* __restrict__ A,
    const unsigned short* __restrict__ B,
    const float* __restrict__ b0,
    float* __restrict__ Of, int M, int N, int K)
{
  extern __shared__ unsigned short lds[];  // A[64*64] @0, B[128*64] @4096 el
  const int tid = threadIdx.x;
  const int lane = tid & 63, w = tid >> 6;
  const int g = lane >> 4, q = lane & 15;
  const long bm = (long)blockIdx.y * 64, bn = (long)blockIdx.x * 128;
  const int NK = K >> 6;

  const int srl = lane >> 3;
  const int scE = ((lane & 7) ^ srl) * 8;
  const int c0 = (g ^ (q & 7)) * 8;
  const int c1 = c0 ^ 32;
  const int aB = q * 64;
  const int bB = (w * 32 + q) * 64;

  f32x4 acc[4][2] = {};
  short8 a[4][2], b[2][2];

#define STAGE_A(jj) do {                                                      \
    _Pragma("unroll")                                                         \
    for (int c_ = 0; c_ < 2; ++c_) {                                          \
      const long row_ = (c_ * 4 + w) * 8 + srl;                               \
      gload_lds16(&A[(bm + row_) * (long)K + (jj) * 64 + scE],                \
                  &lds[(c_ * 4 + w) * 512]);                                  \
    }                                                                         \
  } while (0)

#define STAGE_B(jj) do {                                                      \
    _Pragma("unroll")                                                         \
    for (int c_ = 0; c_ < 4; ++c_) {                                          \
      const long row_ = (c_ * 4 + w) * 8 + srl;                               \
      gload_lds16(&B[(bn + row_) * (long)K + (jj) * 64 + scE],                \
                  &lds[4096 + (c_ * 4 + w) * 512]);                           \
    }                                                                         \
  } while (0)

#define QUAD8(ni)                                                             \
  do {                                                                        \
    __builtin_amdgcn_s_setprio(1);                                            \
    _Pragma("unroll")                                                         \
    for (int mi_ = 0; mi_ < 4; ++mi_) {                                       \
      acc[mi_][ni] = __builtin_amdgcn_mfma_f32_16x16x32_bf16(                 \
          a[mi_][0], b[ni][0], acc[mi_][ni], 0, 0, 0);                        \
      acc[mi_][ni] = __builtin_amdgcn_mfma_f32_16x16x32_bf16(                 \
          a[mi_][1], b[ni][1], acc[mi_][ni], 0, 0, 0);                        \
    }                                                                         \
    __builtin_amdgcn_s_setprio(0);                                            \
  } while (0)

  for (int j = 0; j < NK; ++j) {
    STAGE_A(j);
    STAGE_B(j);
    VM0();                                  // tile landed
    BAR();                                  // all waves see full tile
#pragma unroll
    for (int mi = 0; mi < 4; ++mi) {
      a[mi][0] = *(const short8*)&lds[aB + mi * 1024 + c0];
      a[mi][1] = *(const short8*)&lds[aB + mi * 1024 + c1];
    }
#pragma unroll
    for (int ni = 0; ni < 2; ++ni) {
      b[ni][0] = *(const short8*)&lds[4096 + bB + ni * 1024 + c0];
      b[ni][1] = *(const short8*)&lds[4096 + bB + ni * 1024 + c1];
    }
    QUAD8(0);
    QUAD8(1);
    BAR();                                  // all reads done -> safe to restage
  }

#pragma unroll
  for (int ni = 0; ni < 2; ++ni) {
    const int col = (int)bn + w * 32 + ni * 16 + q;
    const float bv = b0[col];
#pragma unroll
    for (int mi = 0; mi < 4; ++mi)
#pragma unroll
      for (int r = 0; r < 4; ++r) {
        const long row = bm + mi * 16 + 4 * g + r;
        Of[row * (long)N + col] = acc[mi][ni][r] + bv;
      }
  }
#undef STAGE_A
#undef STAGE_B
#undef QUAD8
}

// ---------------- flash attention v15: QK-ahead software pipeline -----------
// R26-verified WIN (66.0 -> 62.3us): base = R24 (gload_lds staging, K/V
// dbuf, Pt path, XCD decode). Per phase t:
//   STAGE_K(t+2)->Kbuf[t&1]; QK(t+1) MFMA chain; exp/pack/Pt/pf of tile t
//   (VALU under the QK MFMAs); PV(t); BAR; STAGE_V(t+2); vmcnt(4); BAR.
// R27's role-split waves REGRESSED (84us: extra barrier + VGPR 156) ->
// reverted to this exact version.
#define KVB 64
__global__ __launch_bounds__(256) void flash_attn(
    const unsigned short* __restrict__ Qb,
    const unsigned short* __restrict__ Kb,
    const unsigned short* __restrict__ VTb,
    unsigned short* __restrict__ attnb)      // [SEQ][HID] bf16
{
  // S (elements): Kt0 @0 | Kt1 @8192 | Vt0 @16384 | Vt1 @24576 | Pt @32768
  extern __shared__ unsigned short S[];      // 36864 us = 72KB
  const int tid = threadIdx.x;
  const int l = tid & 63, w = tid >> 6;
  const int g = l >> 4, q = l & 15;
  const int bid = blockIdx.x;
  const int jj = bid >> 3;
  const int h = ((bid & 7) << 1) | (jj >> 5);   // 2 heads per XCD (R19-proven)
  const int qb = jj & 31;
  const int qrow0 = qb * 64 + w * 16;

  unsigned short* Pw = S + 32768 + w * 1024;

  short8 qf[4];
#pragma unroll
  for (int dc = 0; dc < 4; ++dc)
    qf[dc] = *(const short8*)&Qb[((long)h * SEQ + qrow0 + q) * HD + dc * 32 + g * 8];

  f32x4 oacc[8] = {};
  f32x4 saccA[4], saccB[4];
  const f32x4 zero4 = {};
  float lsum[4] = {0.f, 0.f, 0.f, 0.f};

  const unsigned short* Kg = Kb + (long)h * SEQ * HD;
  const unsigned short* Vg = VTb + (long)h * HD * SEQ;

  // R24-proven staging geometry (pre-swizzled global source, linear LDS dest)
  const int kce = ((l & 15) ^ (l >> 4)) * 8;        // K, even calls
  const int kco = kce ^ 32;                         // K, odd calls
  const int vce = ((l & 7) ^ ((l >> 3) & 7)) * 8;   // V, all calls
  const int krl = l >> 4;
  const int vrl = l >> 3;
  unsigned short* KdB = S + w * 2048;               // + buf*8192 + c*512
  unsigned short* VdB = S + 16384 + w * 2048;

#define STAGE_K(kb_, bufsel) do {                                             \
    const unsigned short* Kp_ = Kg + (long)((kb_) + w * 16 + krl) * HD;       \
    unsigned short* Kd_ = KdB + (bufsel) * 8192;                              \
    gload_lds16(Kp_ + 0 * 4 * HD + kce, Kd_ + 0 * 512);                       \
    gload_lds16(Kp_ + 1 * 4 * HD + kco, Kd_ + 1 * 512);                       \
    gload_lds16(Kp_ + 2 * 4 * HD + kce, Kd_ + 2 * 512);                       \
    gload_lds16(Kp_ + 3 * 4 * HD + kco, Kd_ + 3 * 512);                       \
  } while (0)

#define STAGE_V(kb_, bufsel) do {                                             \
    const unsigned short* Vp_ = Vg + (long)(w * 32 + vrl) * SEQ + (kb_) + vce;\
    unsigned short* Vd_ = VdB + (bufsel) * 8192;                              \
    gload_lds16(Vp_ + 0 * 8 * SEQ, Vd_ + 0 * 512);                            \
    gload_lds16(Vp_ + 1 * 8 * SEQ, Vd_ + 1 * 512);                            \
    gload_lds16(Vp_ + 2 * 8 * SEQ, Vd_ + 2 * 512);                            \
    gload_lds16(Vp_ + 3 * 8 * SEQ, Vd_ + 3 * 512);                            \
  } while (0)

#define QKT(T1, SN) do {                                                      \
    const unsigned short* Kt_ = S + ((T1) & 1) * 8192;                        \
    __builtin_amdgcn_s_setprio(1);                                            \
    _Pragma("unroll")                                                         \
    for (int kc = 0; kc < 4; ++kc) {                                          \
      const int krow_ = kc * 16 + q;                                          \
      const int sw_ = (krow_ & 7) << 4;                                       \
      _Pragma("unroll")                                                       \
      for (int dc = 0; dc < 4; ++dc) {                                        \
        short8 kf_ = *(const short8*)&Kt_[((krow_ * 256 + dc * 64 + g * 16) ^ sw_) >> 1]; \
        SN[kc] = __builtin_amdgcn_mfma_f32_16x16x32_bf16(qf[dc], kf_, SN[kc], 0, 0, 0);   \
      }                                                                       \
    }                                                                         \
    __builtin_amdgcn_s_setprio(0);                                            \
  } while (0)

#define FINISH_PV(T, SC) do {                                                 \
    float p_[4][4];                                                           \
    _Pragma("unroll")                                                         \
    for (int r = 0; r < 4; ++r) {                                             \
      _Pragma("unroll")                                                       \
      for (int kc = 0; kc < 4; ++kc) p_[kc][r] = exp2fast(SC[kc][r]);         \
      lsum[r] += (p_[0][r] + p_[1][r]) + (p_[2][r] + p_[3][r]);               \
    }                                                                         \
    _Pragma("unroll")                                                         \
    for (int r = 0; r < 4; ++r) {                                             \
      const int prow_ = 4 * g + r;                                            \
      const int sw_ = (prow_ & 7) << 4;                                       \
      _Pragma("unroll")                                                       \
      for (int kc = 0; kc < 4; ++kc)                                          \
        Pw[((prow_ * 128 + (kc * 16 + q) * 2) ^ sw_) >> 1] = f2bu_fast(p_[kc][r]); \
    }                                                                         \
    short8 pf_[2];                                                            \
    const int psw_ = (q & 7) << 4;                                            \
    _Pragma("unroll")                                                         \
    for (int ks = 0; ks < 2; ++ks)                                            \
      pf_[ks] = *(const short8*)&Pw[((q * 128 + ks * 64 + g * 16) ^ psw_) >> 1]; \
    const unsigned short* Vt_ = S + 16384 + ((T) & 1) * 8192;                 \
    __builtin_amdgcn_s_setprio(1);                                            \
    _Pragma("unroll")                                                         \
    for (int dt = 0; dt < 8; ++dt) {                                          \
      const int vrow_ = dt * 16 + q;                                          \
      _Pragma("unroll")                                                       \
      for (int ks = 0; ks < 2; ++ks) {                                        \
        short8 vf_ = *(const short8*)&Vt_[((vrow_ * 128 + ks * 64 + g * 16) ^ psw_) >> 1]; \
        oacc[dt] = __builtin_amdgcn_mfma_f32_16x16x32_bf16(pf_[ks], vf_, oacc[dt], 0, 0, 0); \
      }                                                                       \
    }                                                                         \
    __builtin_amdgcn_s_setprio(0);                                            \
  } while (0)

#define PHASE(T, SC, SN) do {                                                 \
    if ((T) + 2 < 32) STAGE_K(((T) + 2) * KVB, (T) & 1);                      \
    if ((T) + 1 < 32) {                                                       \
      _Pragma("unroll")                                                       \
      for (int kc = 0; kc < 4; ++kc) SN[kc] = zero4;                          \
      QKT((T) + 1, SN);                                                       \
    }                                                                         \
    FINISH_PV(T, SC);                                                         \
    BAR();                                                                    \
    if ((T) + 2 < 32) STAGE_V(((T) + 2) * KVB, (T) & 1);                      \
    if ((T) <= 29) { VM4(); } else { VM0(); }                                 \
    BAR();                                                                    \
  } while (0)

  // ---- prologue: tiles 0,1 staged; QK(0) computed; barrier so no wave
  // overwrites Kbuf0 (phase 0's STAGE_K(2)) before all waves read it.
  STAGE_K(0, 0); STAGE_V(0, 0);
  STAGE_K(KVB, 1); STAGE_V(KVB, 1);
  VM0();
  BAR();
#pragma unroll
  for (int kc = 0; kc < 4; ++kc) saccA[kc] = zero4;
  QKT(0, saccA);
  BAR();

  for (int t = 0; t < 32; t += 2) {
    PHASE(t, saccA, saccB);
    PHASE(t + 1, saccB, saccA);
  }

  // sum exp over the 16 q-lanes (KV columns live on q within each 16-lane grp)
#pragma unroll
  for (int off = 1; off < 16; off <<= 1)
#pragma unroll
    for (int r = 0; r < 4; ++r) lsum[r] += __shfl_xor(lsum[r], off);

  const float rl0 = 1.f / lsum[0], rl1 = 1.f / lsum[1];
  const float rl2 = 1.f / lsum[2], rl3 = 1.f / lsum[3];
#pragma unroll
  for (int dt = 0; dt < 8; ++dt) {
    const long colb = (long)h * HD + dt * 16 + q;
    attnb[(long)(qrow0 + 4 * g + 0) * HID + colb] = f2bu(oacc[dt][0] * rl0);
    attnb[(long)(qrow0 + 4 * g + 1) * HID + colb] = f2bu(oacc[dt][1] * rl1);
    attnb[(long)(qrow0 + 4 * g + 2) * HID + colb] = f2bu(oacc[dt][2] * rl2);
    attnb[(long)(qrow0 + 4 * g + 3) * HID + colb] = f2bu(oacc[dt][3] * rl3);
  }
#undef STAGE_K
#undef STAGE_V
#undef QKT
#undef FINISH_PV
#undef PHASE
}

extern "C" void kernel_launch(void* const* d_in, const int* in_sizes, int n_in,
                              void* d_out, int out_size, void* d_ws, size_t ws_size,
                              hipStream_t stream)
{
  const float* x  = (const float*)d_in[0];
  const float* wq = (const float*)d_in[1];
  const float* bq = (const float*)d_in[2];
  const float* wk = (const float*)d_in[3];
  const float* bk = (const float*)d_in[4];
  const float* wv = (const float*)d_in[5];
  const float* bv = (const float*)d_in[6];
  const float* wo = (const float*)d_in[7];
  const float* bo = (const float*)d_in[8];

  const long NEL = (long)HID * HID;
  unsigned short* Xb   = (unsigned short*)d_ws;
  unsigned short* Wqkv = Xb + NEL;
  unsigned short* Wob  = Wqkv + 3 * NEL;
  unsigned short* Qbuf = Wob + NEL;
  unsigned short* Kbuf = Qbuf + NEL;
  unsigned short* VTb  = Kbuf + NEL;
  unsigned short* Attn = VTb + NEL;

  // one-time opt-in for 72KB dynamic LDS (host-side, graph-capture safe)
  static bool attrDone = false;
  if (!attrDone) {
    hipFuncSetAttribute(reinterpret_cast<const void*>(flash_attn),
                        hipFuncAttributeMaxDynamicSharedMemorySize, 73728);
    attrDone = true;
  }

  cvt_kernel<<<dim3(512, 5), 256, 0, stream>>>(
      x, wq, wk, wv, wo, Xb, Wqkv, Wqkv + NEL, Wqkv + 2 * NEL, Wob, (int)NEL);

  gemm97<4><<<dim3(48, 16), 256, 32768, stream>>>(
      Xb, Wqkv, bq, bk, bv, Qbuf, Kbuf, VTb, nullptr, SEQ, 3 * HID, HID);

  flash_attn<<<dim3(512), 256, 73728, stream>>>(Qbuf, Kbuf, VTb, Attn);

  gemm97o<<<dim3(16, 32), 256, 24576, stream>>>(
      Attn, Wob, bo, (float*)d_out, SEQ, HID, HID);
}

// Round 15
// 167.031 us; speedup vs baseline: 1.0940x; 1.0115x over previous
//
#include <hip/hip_runtime.h>
#include <hip/hip_bf16.h>
#include <stdint.h>

#define SEQ 2048
#define HID 2048
#define NH 16
#define HD 128
// 1/sqrt(128) * log2(e): softmax runs in exp2 domain
#define QSCALE_L2E 0.1275304429019769f

typedef __attribute__((ext_vector_type(4))) float f32x4;
typedef __attribute__((ext_vector_type(8))) short short8;
typedef __attribute__((ext_vector_type(4))) float f4;
typedef __attribute__((ext_vector_type(4))) unsigned short us4;

__device__ __forceinline__ unsigned short f2bu(float f) {
  union { float f; unsigned int u; } c; c.f = f;
  unsigned int u = c.u + 0x7fffu + ((c.u >> 16) & 1u);  // RNE, finite inputs
  return (unsigned short)(u >> 16);
}

__device__ __forceinline__ unsigned short f2bu_fast(float f) {
  union { float f; unsigned int u; } c; c.f = f;
  return (unsigned short)((c.u + 0x8000u) >> 16);
}

__device__ __forceinline__ float b2f(unsigned short u) {
  union { unsigned int u; float f; } c; c.u = ((unsigned int)u) << 16; return c.f;
}

__device__ __forceinline__ float exp2fast(float x) {
  float r; asm("v_exp_f32 %0, %1" : "=v"(r) : "v"(x)); return r;
}

__device__ __forceinline__ void gload_lds16(const void* g, void* l) {
  __builtin_amdgcn_global_load_lds((const __attribute__((address_space(1))) void*)g,
                                   (__attribute__((address_space(3))) void*)l, 16, 0, 0);
}

#define BAR() __builtin_amdgcn_s_barrier()
#define LGKM0() do { asm volatile("s_waitcnt lgkmcnt(0)" ::: "memory"); __builtin_amdgcn_sched_barrier(0); } while (0)
#define VM6()   do { asm volatile("s_waitcnt vmcnt(6)"   ::: "memory"); __builtin_amdgcn_sched_barrier(0); } while (0)
#define VM4()   do { asm volatile("s_waitcnt vmcnt(4)"   ::: "memory"); __builtin_amdgcn_sched_barrier(0); } while (0)
#define VM0()   do { asm volatile("s_waitcnt vmcnt(0)"   ::: "memory"); __builtin_amdgcn_sched_barrier(0); } while (0)

// ---------------- fp32 -> bf16 convert, 5 equal-size arrays (32B/thread) ----
__global__ __launch_bounds__(256) void cvt_kernel(
    const float* __restrict__ s0, const float* __restrict__ s1,
    const float* __restrict__ s2, const float* __restrict__ s3,
    const float* __restrict__ s4,
    unsigned short* __restrict__ d0, unsigned short* __restrict__ d1,
    unsigned short* __restrict__ d2, unsigned short* __restrict__ d3,
    unsigned short* __restrict__ d4, int n)
{
  const float* s; unsigned short* d;
  switch (blockIdx.y) {
    case 0: s = s0; d = d0; break;
    case 1: s = s1; d = d1; break;
    case 2: s = s2; d = d2; break;
    case 3: s = s3; d = d3; break;
    default: s = s4; d = d4; break;
  }
  const int stride = gridDim.x * blockDim.x;
  for (int i = blockIdx.x * blockDim.x + threadIdx.x; i * 8 < n; i += stride) {
    f4 v0 = *(const f4*)&s[i * 8];
    f4 v1 = *(const f4*)&s[i * 8 + 4];
    short8 o;
    o[0] = (short)f2bu(v0[0]); o[1] = (short)f2bu(v0[1]);
    o[2] = (short)f2bu(v0[2]); o[3] = (short)f2bu(v0[3]);
    o[4] = (short)f2bu(v1[0]); o[5] = (short)f2bu(v1[1]);
    o[6] = (short)f2bu(v1[2]); o[7] = (short)f2bu(v1[3]);
    *(short8*)&d[i * 8] = o;
  }
}

// ---------------- 128x128 bf16 GEMM, m97-style single-buffer (QKV) ----------
// R18-verified WIN: BM=BN=128, BK=64, 4 waves (2Mx2N), per-wave 64x64.
// SINGLE 32KB LDS buffer + launch_bounds(256,3) -> 3 blocks/CU (m114
// cross-block MFMA/staging overlap covers the per-tile drain).
// R29: 1D grid 768 + XCD-aware swizzle (T1): swz = (bid&7)*96 + bid>>3,
// column-major decode (bx=swz>>4, by=swz&15) -> each XCD owns 6 consecutive
// B-panels (3MB, fits 4MB per-XCD L2) across all 16 row-blocks; B re-reads
// become L2 hits. Bijective (768 % 8 == 0); perf-only change.
template<int MODE>
__global__ __launch_bounds__(256, 3) void gemm97(
    const unsigned short* __restrict__ A,
    const unsigned short* __restrict__ B,
    const float* __restrict__ b0, const float* __restrict__ b1, const float* __restrict__ b2,
    unsigned short* __restrict__ O0, unsigned short* __restrict__ O1, unsigned short* __restrict__ O2,
    float* __restrict__ Of, int M, int N, int K)
{
  extern __shared__ unsigned short lds[];  // A[128*64] @0, B[128*64] @8192 el
  const int tid = threadIdx.x;
  const int lane = tid & 63, w = tid >> 6;
  const int g = lane >> 4, q = lane & 15;
  const int wgM = w >> 1, wgN = w & 1;     // 2M x 2N wave grid
  // XCD swizzle: nwg = gridDim.x (multiple of 8); chunk = nwg/8 per XCD.
  const int bid = blockIdx.x;
  const int swz = (bid & 7) * ((int)gridDim.x >> 3) + (bid >> 3);
  const long bm = (long)(swz & 15) * 128;  // by (M/128 == 16)
  const long bn = (long)(swz >> 4) * 128;  // bx
  const int NK = K >> 6;

  const int srl = lane >> 3;
  const int scE = ((lane & 7) ^ srl) * 8;
  const int c0 = (g ^ (q & 7)) * 8;
  const int c1 = c0 ^ 32;
  const int aB = (wgM * 64 + q) * 64;
  const int bB = (wgN * 64 + q) * 64;

  f32x4 acc[4][4] = {};
  short8 a[4][2], b[4][2];

#define STAGE(gp, gbase, jj, ldsOff) do {                                     \
    _Pragma("unroll")                                                         \
    for (int c_ = 0; c_ < 4; ++c_) {                                          \
      const long row_ = (c_ * 4 + w) * 8 + srl;                               \
      gload_lds16(&(gp)[((gbase) + row_) * (long)K + (jj) * 64 + scE],        \
                  &lds[(ldsOff) + (c_ * 4 + w) * 512]);                       \
    }                                                                         \
  } while (0)

#define QUADD(n0, n1)                                                         \
  do {                                                                        \
    __builtin_amdgcn_s_setprio(1);                                            \
    _Pragma("unroll")                                                         \
    for (int mi_ = 0; mi_ < 4; ++mi_) {                                       \
      acc[mi_][n0] = __builtin_amdgcn_mfma_f32_16x16x32_bf16(                 \
          a[mi_][0], b[n0][0], acc[mi_][n0], 0, 0, 0);                        \
      acc[mi_][n0] = __builtin_amdgcn_mfma_f32_16x16x32_bf16(                 \
          a[mi_][1], b[n0][1], acc[mi_][n0], 0, 0, 0);                        \
      acc[mi_][n1] = __builtin_amdgcn_mfma_f32_16x16x32_bf16(                 \
          a[mi_][0], b[n1][0], acc[mi_][n1], 0, 0, 0);                        \
      acc[mi_][n1] = __builtin_amdgcn_mfma_f32_16x16x32_bf16(                 \
          a[mi_][1], b[n1][1], acc[mi_][n1], 0, 0, 0);                        \
    }                                                                         \
    __builtin_amdgcn_s_setprio(0);                                            \
  } while (0)

  for (int j = 0; j < NK; ++j) {
    STAGE(A, bm, j, 0);
    STAGE(B, bn, j, 8192);
    VM0();                                  // tile landed
    BAR();                                  // all waves see full tile
#pragma unroll
    for (int mi = 0; mi < 4; ++mi) {
      a[mi][0] = *(const short8*)&lds[aB + mi * 1024 + c0];
      a[mi][1] = *(const short8*)&lds[aB + mi * 1024 + c1];
    }
#pragma unroll
    for (int ni = 0; ni < 4; ++ni) {
      b[ni][0] = *(const short8*)&lds[8192 + bB + ni * 1024 + c0];
      b[ni][1] = *(const short8*)&lds[8192 + bB + ni * 1024 + c1];
    }
    QUADD(0, 1);
    QUADD(2, 3);
    BAR();                                  // all reads done -> safe to restage
  }

#pragma unroll
  for (int ni = 0; ni < 4; ++ni) {
    const int col = (int)bn + wgN * 64 + ni * 16 + q;
    float bv;
    if (MODE == 4) {
      const int which = col >> 11, c = col & 2047;
      const float* bp = which == 0 ? b0 : (which == 1 ? b1 : b2);
      bv = bp[c];
    } else {
      bv = b0[col];
    }
#pragma unroll
    for (int mi = 0; mi < 4; ++mi)
#pragma unroll
      for (int r = 0; r < 4; ++r) {
        const long row = bm + wgM * 64 + mi * 16 + 4 * g + r;
        const float v = acc[mi][ni][r] + bv;
        if (MODE == 4) {
          const int which = col >> 11, c = col & 2047, head = c >> 7, d = c & 127;
          if (which == 0)      O0[((long)head * SEQ + row) * HD + d] = f2bu(v * QSCALE_L2E);
          else if (which == 1) O1[((long)head * SEQ + row) * HD + d] = f2bu(v);
          else                 O2[((long)head * HD + d) * SEQ + row] = f2bu(v);
        } else {
          Of[row * (long)N + col] = v;
        }
      }
  }
#undef STAGE
#undef QUADD
}

// ---------------- 64x128 bf16 GEMM  C = A[M,K] * B[N,K]^T + bias ------------
// Out-projection: dbuf 2-barrier structure. R28 proved single-buffer REGRESSES
// at this grid (512 blocks = 2 blocks/CU: no third block to hide the VM0
// drain). dbuf for 2-block/CU grids, single-buffer for >=3.
template<int MODE>
__global__ __launch_bounds__(256, 2) void gemm128(
    const unsigned short* __restrict__ A,
    const unsigned short* __restrict__ B,
    const float* __restrict__ b0, const float* __restrict__ b1, const float* __restrict__ b2,
    unsigned short* __restrict__ O0, unsigned short* __restrict__ O1, unsigned short* __restrict__ O2,
    float* __restrict__ Of, int M, int N, int K)
{
  constexpr int ASZ = 64 * 64;
  constexpr int BSZ = 128 * 64;

  extern __shared__ unsigned short lds[];
  const int tid = threadIdx.x;
  const int lane = tid & 63, w = tid >> 6;
  const int g = lane >> 4, q = lane & 15;
  const long bm = (long)blockIdx.y * 64, bn = (long)blockIdx.x * 128;
  const int NK = K >> 6;

  const int srl = lane >> 3;
  const int scE = ((lane & 7) ^ srl) * 8;
  const int c0 = (g ^ (q & 7)) * 8;
  const int c1 = c0 ^ 32;
  const int aB = q * 64;
  const int bB = (w * 32 + q) * 64;

  f32x4 acc[4][2] = {};
  short8 a[4][2], b[2][2];

#define STAGE_A(jj) do {                                                      \
    unsigned short* dst_ = lds + (((jj) & 1) ? ASZ : 0);                      \
    _Pragma("unroll")                                                         \
    for (int c_ = 0; c_ < 2; ++c_) {                                          \
      const long row_ = (c_ * 4 + w) * 8 + srl;                               \
      gload_lds16(&A[(bm + row_) * (long)K + (jj) * 64 + scE],                \
                  &dst_[(c_ * 4 + w) * 512]);                                 \
    }                                                                         \
  } while (0)

#define STAGE_B(jj) do {                                                      \
    unsigned short* dst_ = lds + 2 * ASZ + (((jj) & 1) ? BSZ : 0);            \
    _Pragma("unroll")                                                         \
    for (int c_ = 0; c_ < 4; ++c_) {                                          \
      const long row_ = (c_ * 4 + w) * 8 + srl;                               \
      gload_lds16(&B[(bn + row_) * (long)K + (jj) * 64 + scE],                \
                  &dst_[(c_ * 4 + w) * 512]);                                 \
    }                                                                         \
  } while (0)

#define QUAD8(ni)                                                             \
  do {                                                                        \
    __builtin_amdgcn_s_setprio(1);                                            \
    _Pragma("unroll")                                                         \
    for (int mi_ = 0; mi_ < 4; ++mi_) {                                       \
      acc[mi_][ni] = __builtin_amdgcn_mfma_f32_16x16x32_bf16(                 \
          a[mi_][0], b[ni][0], acc[mi_][ni], 0, 0, 0);                        \
      acc[mi_][ni] = __builtin_amdgcn_mfma_f32_16x16x32_bf16(                 \
          a[mi_][1], b[ni][1], acc[mi_][ni], 0, 0, 0);                        \
    }                                                                         \
    __builtin_amdgcn_s_setprio(0);                                            \
  } while (0)

  STAGE_A(0); STAGE_B(0);
  STAGE_A(1); STAGE_B(1);
  VM6();
  BAR();

  for (int j = 0; j < NK; ++j) {
    unsigned short* At = lds + ((j & 1) ? ASZ : 0);
    unsigned short* Bt = lds + 2 * ASZ + ((j & 1) ? BSZ : 0);

#pragma unroll
    for (int mi = 0; mi < 4; ++mi) {
      a[mi][0] = *(const short8*)&At[aB + mi * 1024 + c0];
      a[mi][1] = *(const short8*)&At[aB + mi * 1024 + c1];
    }
#pragma unroll
    for (int ni = 0; ni < 2; ++ni) {
      b[ni][0] = *(const short8*)&Bt[bB + ni * 1024 + c0];
      b[ni][1] = *(const short8*)&Bt[bB + ni * 1024 + c1];
    }
    QUAD8(0);
    LGKM0();
    BAR();                                  // (a)
    if (j + 2 < NK) { STAGE_A(j + 2); STAGE_B(j + 2); }
    QUAD8(1);
    if (j < NK - 2) { VM6(); } else { VM0(); }
    BAR();                                  // (b)
  }

#pragma unroll
  for (int ni = 0; ni < 2; ++ni) {
    const int col = (int)bn + w * 32 + ni * 16 + q;
    float bv;
    if (MODE == 4) {
      const int which = col >> 11, c = col & 2047;
      const float* bp = which == 0 ? b0 : (which == 1 ? b1 : b2);
      bv = bp[c];
    } else {
      bv = b0[col];
    }
#pragma unroll
    for (int mi = 0; mi < 4; ++mi)
#pragma unroll
      for (int r = 0; r < 4; ++r) {
        const long row = bm + mi * 16 + 4 * g + r;
        const float v = acc[mi][ni][r] + bv;
        if (MODE == 4) {
          const int which = col >> 11, c = col & 2047, head = c >> 7, d = c & 127;
          if (which == 0)      O0[((long)head * SEQ + row) * HD + d] = f2bu(v * QSCALE_L2E);
          else if (which == 1) O1[((long)head * SEQ + row) * HD + d] = f2bu(v);
          else                 O2[((long)head * HD + d) * SEQ + row] = f2bu(v);
        } else {
          Of[row * (long)N + col] = v;
        }
      }
  }
#undef STAGE_A
#undef STAGE_B
#undef QUAD8
}

// ---------------- flash attention v15: QK-ahead software pipeline -----------
// R26-verified WIN (66.0 -> 62.3us): base = R24 (gload_lds staging, K/V
// dbuf, Pt path, XCD decode). Per phase t:
//   STAGE_K(t+2)->Kbuf[t&1]; QK(t+1) MFMA chain; exp/pack/Pt/pf of tile t
//   (VALU under the QK MFMAs); PV(t); BAR; STAGE_V(t+2); vmcnt(4); BAR.
// R27's role-split waves REGRESSED (84us) -> this exact version is final.
#define KVB 64
__global__ __launch_bounds__(256) void flash_attn(
    const unsigned short* __restrict__ Qb,
    const unsigned short* __restrict__ Kb,
    const unsigned short* __restrict__ VTb,
    unsigned short* __restrict__ attnb)      // [SEQ][HID] bf16
{
  // S (elements): Kt0 @0 | Kt1 @8192 | Vt0 @16384 | Vt1 @24576 | Pt @32768
  extern __shared__ unsigned short S[];      // 36864 us = 72KB
  const int tid = threadIdx.x;
  const int l = tid & 63, w = tid >> 6;
  const int g = l >> 4, q = l & 15;
  const int bid = blockIdx.x;
  const int jj = bid >> 3;
  const int h = ((bid & 7) << 1) | (jj >> 5);   // 2 heads per XCD (R19-proven)
  const int qb = jj & 31;
  const int qrow0 = qb * 64 + w * 16;

  unsigned short* Pw = S + 32768 + w * 1024;

  short8 qf[4];
#pragma unroll
  for (int dc = 0; dc < 4; ++dc)
    qf[dc] = *(const short8*)&Qb[((long)h * SEQ + qrow0 + q) * HD + dc * 32 + g * 8];

  f32x4 oacc[8] = {};
  f32x4 saccA[4], saccB[4];
  const f32x4 zero4 = {};
  float lsum[4] = {0.f, 0.f, 0.f, 0.f};

  const unsigned short* Kg = Kb + (long)h * SEQ * HD;
  const unsigned short* Vg = VTb + (long)h * HD * SEQ;

  // R24-proven staging geometry (pre-swizzled global source, linear LDS dest)
  const int kce = ((l & 15) ^ (l >> 4)) * 8;        // K, even calls
  const int kco = kce ^ 32;                         // K, odd calls
  const int vce = ((l & 7) ^ ((l >> 3) & 7)) * 8;   // V, all calls
  const int krl = l >> 4;
  const int vrl = l >> 3;
  unsigned short* KdB = S + w * 2048;               // + buf*8192 + c*512
  unsigned short* VdB = S + 16384 + w * 2048;

#define STAGE_K(kb_, bufsel) do {                                             \
    const unsigned short* Kp_ = Kg + (long)((kb_) + w * 16 + krl) * HD;       \
    unsigned short* Kd_ = KdB + (bufsel) * 8192;                              \
    gload_lds16(Kp_ + 0 * 4 * HD + kce, Kd_ + 0 * 512);                       \
    gload_lds16(Kp_ + 1 * 4 * HD + kco, Kd_ + 1 * 512);                       \
    gload_lds16(Kp_ + 2 * 4 * HD + kce, Kd_ + 2 * 512);                       \
    gload_lds16(Kp_ + 3 * 4 * HD + kco, Kd_ + 3 * 512);                       \
  } while (0)

#define STAGE_V(kb_, bufsel) do {                                             \
    const unsigned short* Vp_ = Vg + (long)(w * 32 + vrl) * SEQ + (kb_) + vce;\
    unsigned short* Vd_ = VdB + (bufsel) * 8192;                              \
    gload_lds16(Vp_ + 0 * 8 * SEQ, Vd_ + 0 * 512);                            \
    gload_lds16(Vp_ + 1 * 8 * SEQ, Vd_ + 1 * 512);                            \
    gload_lds16(Vp_ + 2 * 8 * SEQ, Vd_ + 2 * 512);                            \
    gload_lds16(Vp_ + 3 * 8 * SEQ, Vd_ + 3 * 512);                            \
  } while (0)

#define QKT(T1, SN) do {                                                      \
    const unsigned short* Kt_ = S + ((T1) & 1) * 8192;                        \
    __builtin_amdgcn_s_setprio(1);                                            \
    _Pragma("unroll")                                                         \
    for (int kc = 0; kc < 4; ++kc) {                                          \
      const int krow_ = kc * 16 + q;                                          \
      const int sw_ = (krow_ & 7) << 4;                                       \
      _Pragma("unroll")                                                       \
      for (int dc = 0; dc < 4; ++dc) {                                        \
        short8 kf_ = *(const short8*)&Kt_[((krow_ * 256 + dc * 64 + g * 16) ^ sw_) >> 1]; \
        SN[kc] = __builtin_amdgcn_mfma_f32_16x16x32_bf16(qf[dc], kf_, SN[kc], 0, 0, 0);   \
      }                                                                       \
    }                                                                         \
    __builtin_amdgcn_s_setprio(0);                                            \
  } while (0)

#define FINISH_PV(T, SC) do {                                                 \
    float p_[4][4];                                                           \
    _Pragma("unroll")                                                         \
    for (int r = 0; r < 4; ++r) {                                             \
      _Pragma("unroll")                                                       \
      for (int kc = 0; kc < 4; ++kc) p_[kc][r] = exp2fast(SC[kc][r]);         \
      lsum[r] += (p_[0][r] + p_[1][r]) + (p_[2][r] + p_[3][r]);               \
    }                                                                         \
    _Pragma("unroll")                                                         \
    for (int r = 0; r < 4; ++r) {                                             \
      const int prow_ = 4 * g + r;                                            \
      const int sw_ = (prow_ & 7) << 4;                                       \
      _Pragma("unroll")                                                       \
      for (int kc = 0; kc < 4; ++kc)                                          \
        Pw[((prow_ * 128 + (kc * 16 + q) * 2) ^ sw_) >> 1] = f2bu_fast(p_[kc][r]); \
    }                                                                         \
    short8 pf_[2];                                                            \
    const int psw_ = (q & 7) << 4;                                            \
    _Pragma("unroll")                                                         \
    for (int ks = 0; ks < 2; ++ks)                                            \
      pf_[ks] = *(const short8*)&Pw[((q * 128 + ks * 64 + g * 16) ^ psw_) >> 1]; \
    const unsigned short* Vt_ = S + 16384 + ((T) & 1) * 8192;                 \
    __builtin_amdgcn_s_setprio(1);                                            \
    _Pragma("unroll")                                                         \
    for (int dt = 0; dt < 8; ++dt) {                                          \
      const int vrow_ = dt * 16 + q;                                          \
      _Pragma("unroll")                                                       \
      for (int ks = 0; ks < 2; ++ks) {                                        \
        short8 vf_ = *(const short8*)&Vt_[((vrow_ * 128 + ks * 64 + g * 16) ^ psw_) >> 1]; \
        oacc[dt] = __builtin_amdgcn_mfma_f32_16x16x32_bf16(pf_[ks], vf_, oacc[dt], 0, 0, 0); \
      }                                                                       \
    }                                                                         \
    __builtin_amdgcn_s_setprio(0);                                            \
  } while (0)

#define PHASE(T, SC, SN) do {                                                 \
    if ((T) + 2 < 32) STAGE_K(((T) + 2) * KVB, (T) & 1);                      \
    if ((T) + 1 < 32) {                                                       \
      _Pragma("unroll")                                                       \
      for (int kc = 0; kc < 4; ++kc) SN[kc] = zero4;                          \
      QKT((T) + 1, SN);                                                       \
    }                                                                         \
    FINISH_PV(T, SC);                                                         \
    BAR();                                                                    \
    if ((T) + 2 < 32) STAGE_V(((T) + 2) * KVB, (T) & 1);                      \
    if ((T) <= 29) { VM4(); } else { VM0(); }                                 \
    BAR();                                                                    \
  } while (0)

  // ---- prologue: tiles 0,1 staged; QK(0) computed; barrier so no wave
  // overwrites Kbuf0 (phase 0's STAGE_K(2)) before all waves read it.
  STAGE_K(0, 0); STAGE_V(0, 0);
  STAGE_K(KVB, 1); STAGE_V(KVB, 1);
  VM0();
  BAR();
#pragma unroll
  for (int kc = 0; kc < 4; ++kc) saccA[kc] = zero4;
  QKT(0, saccA);
  BAR();

  for (int t = 0; t < 32; t += 2) {
    PHASE(t, saccA, saccB);
    PHASE(t + 1, saccB, saccA);
  }

  // sum exp over the 16 q-lanes (KV columns live on q within each 16-lane grp)
#pragma unroll
  for (int off = 1; off < 16; off <<= 1)
#pragma unroll
    for (int r = 0; r < 4; ++r) lsum[r] += __shfl_xor(lsum[r], off);

  const float rl0 = 1.f / lsum[0], rl1 = 1.f / lsum[1];
  const float rl2 = 1.f / lsum[2], rl3 = 1.f / lsum[3];
#pragma unroll
  for (int dt = 0; dt < 8; ++dt) {
    const long colb = (long)h * HD + dt * 16 + q;
    attnb[(long)(qrow0 + 4 * g + 0) * HID + colb] = f2bu(oacc[dt][0] * rl0);
    attnb[(long)(qrow0 + 4 * g + 1) * HID + colb] = f2bu(oacc[dt][1] * rl1);
    attnb[(long)(qrow0 + 4 * g + 2) * HID + colb] = f2bu(oacc[dt][2] * rl2);
    attnb[(long)(qrow0 + 4 * g + 3) * HID + colb] = f2bu(oacc[dt][3] * rl3);
  }
#undef STAGE_K
#undef STAGE_V
#undef QKT
#undef FINISH_PV
#undef PHASE
}

extern "C" void kernel_launch(void* const* d_in, const int* in_sizes, int n_in,
                              void* d_out, int out_size, void* d_ws, size_t ws_size,
                              hipStream_t stream)
{
  const float* x  = (const float*)d_in[0];
  const float* wq = (const float*)d_in[1];
  const float* bq = (const float*)d_in[2];
  const float* wk = (const float*)d_in[3];
  const float* bk = (const float*)d_in[4];
  const float* wv = (const float*)d_in[5];
  const float* bv = (const float*)d_in[6];
  const float* wo = (const float*)d_in[7];
  const float* bo = (const float*)d_in[8];

  const long NEL = (long)HID * HID;
  unsigned short* Xb   = (unsigned short*)d_ws;
  unsigned short* Wqkv = Xb + NEL;
  unsigned short* Wob  = Wqkv + 3 * NEL;
  unsigned short* Qbuf = Wob + NEL;
  unsigned short* Kbuf = Qbuf + NEL;
  unsigned short* VTb  = Kbuf + NEL;
  unsigned short* Attn = VTb + NEL;

  // one-time opt-in for 72KB dynamic LDS (host-side, graph-capture safe)
  static bool attrDone = false;
  if (!attrDone) {
    hipFuncSetAttribute(reinterpret_cast<const void*>(flash_attn),
                        hipFuncAttributeMaxDynamicSharedMemorySize, 73728);
    attrDone = true;
  }

  cvt_kernel<<<dim3(512, 5), 256, 0, stream>>>(
      x, wq, wk, wv, wo, Xb, Wqkv, Wqkv + NEL, Wqkv + 2 * NEL, Wob, (int)NEL);

  gemm97<4><<<dim3(768), 256, 32768, stream>>>(
      Xb, Wqkv, bq, bk, bv, Qbuf, Kbuf, VTb, nullptr, SEQ, 3 * HID, HID);

  flash_attn<<<dim3(512), 256, 73728, stream>>>(Qbuf, Kbuf, VTb, Attn);

  gemm128<3><<<dim3(16, 32), 256, 49152, stream>>>(
      Attn, Wob, bo, nullptr, nullptr, nullptr, nullptr, nullptr,
      (float*)d_out, SEQ, HID, HID);
}

// Round 16
// 162.186 us; speedup vs baseline: 1.1267x; 1.0299x over previous
//
#include <hip/hip_runtime.h>
#include <hip/hip_bf16.h>
#include <stdint.h>

#define SEQ 2048
#define HID 2048
#define NH 16
#define HD 128
// 1/sqrt(128) * log2(e): softmax runs in exp2 domain
#define QSCALE_L2E 0.1275304429019769f

typedef __attribute__((ext_vector_type(4))) float f32x4;
typedef __attribute__((ext_vector_type(8))) short short8;
typedef __attribute__((ext_vector_type(4))) float f4;
typedef __attribute__((ext_vector_type(4))) unsigned short us4;

__device__ __forceinline__ unsigned short f2bu(float f) {
  union { float f; unsigned int u; } c; c.f = f;
  unsigned int u = c.u + 0x7fffu + ((c.u >> 16) & 1u);  // RNE, finite inputs
  return (unsigned short)(u >> 16);
}

__device__ __forceinline__ unsigned short f2bu_fast(float f) {
  union { float f; unsigned int u; } c; c.f = f;
  return (unsigned short)((c.u + 0x8000u) >> 16);
}

__device__ __forceinline__ float b2f(unsigned short u) {
  union { unsigned int u; float f; } c; c.u = ((unsigned int)u) << 16; return c.f;
}

__device__ __forceinline__ float exp2fast(float x) {
  float r; asm("v_exp_f32 %0, %1" : "=v"(r) : "v"(x)); return r;
}

__device__ __forceinline__ void gload_lds16(const void* g, void* l) {
  __builtin_amdgcn_global_load_lds((const __attribute__((address_space(1))) void*)g,
                                   (__attribute__((address_space(3))) void*)l, 16, 0, 0);
}

#define BAR() __builtin_amdgcn_s_barrier()
#define LGKM0() do { asm volatile("s_waitcnt lgkmcnt(0)" ::: "memory"); __builtin_amdgcn_sched_barrier(0); } while (0)
#define VM6()   do { asm volatile("s_waitcnt vmcnt(6)"   ::: "memory"); __builtin_amdgcn_sched_barrier(0); } while (0)
#define VM4()   do { asm volatile("s_waitcnt vmcnt(4)"   ::: "memory"); __builtin_amdgcn_sched_barrier(0); } while (0)
#define VM0()   do { asm volatile("s_waitcnt vmcnt(0)"   ::: "memory"); __builtin_amdgcn_sched_barrier(0); } while (0)

// ---------------- fp32 -> bf16 convert, 5 equal-size arrays (32B/thread) ----
__global__ __launch_bounds__(256) void cvt_kernel(
    const float* __restrict__ s0, const float* __restrict__ s1,
    const float* __restrict__ s2, const float* __restrict__ s3,
    const float* __restrict__ s4,
    unsigned short* __restrict__ d0, unsigned short* __restrict__ d1,
    unsigned short* __restrict__ d2, unsigned short* __restrict__ d3,
    unsigned short* __restrict__ d4, int n)
{
  const float* s; unsigned short* d;
  switch (blockIdx.y) {
    case 0: s = s0; d = d0; break;
    case 1: s = s1; d = d1; break;
    case 2: s = s2; d = d2; break;
    case 3: s = s3; d = d3; break;
    default: s = s4; d = d4; break;
  }
  const int stride = gridDim.x * blockDim.x;
  for (int i = blockIdx.x * blockDim.x + threadIdx.x; i * 8 < n; i += stride) {
    f4 v0 = *(const f4*)&s[i * 8];
    f4 v1 = *(const f4*)&s[i * 8 + 4];
    short8 o;
    o[0] = (short)f2bu(v0[0]); o[1] = (short)f2bu(v0[1]);
    o[2] = (short)f2bu(v0[2]); o[3] = (short)f2bu(v0[3]);
    o[4] = (short)f2bu(v1[0]); o[5] = (short)f2bu(v1[1]);
    o[6] = (short)f2bu(v1[2]); o[7] = (short)f2bu(v1[3]);
    *(short8*)&d[i * 8] = o;
  }
}

// ---------------- 128x128 bf16 GEMM, m97-style single-buffer (QKV) ----------
// R18-verified WIN: BM=BN=128, BK=64, 4 waves (2Mx2N), per-wave 64x64.
// SINGLE 32KB LDS buffer + launch_bounds(256,3) -> 3 blocks/CU (m114
// cross-block MFMA/staging overlap covers the per-tile drain).
// R29's XCD swizzle REGRESSED (write-combining loss: WRITE 27->47MB, QKV
// 50->69us) -> default 2D x-major dispatch restored. Do not permute blocks.
template<int MODE>
__global__ __launch_bounds__(256, 3) void gemm97(
    const unsigned short* __restrict__ A,
    const unsigned short* __restrict__ B,
    const float* __restrict__ b0, const float* __restrict__ b1, const float* __restrict__ b2,
    unsigned short* __restrict__ O0, unsigned short* __restrict__ O1, unsigned short* __restrict__ O2,
    float* __restrict__ Of, int M, int N, int K)
{
  extern __shared__ unsigned short lds[];  // A[128*64] @0, B[128*64] @8192 el
  const int tid = threadIdx.x;
  const int lane = tid & 63, w = tid >> 6;
  const int g = lane >> 4, q = lane & 15;
  const int wgM = w >> 1, wgN = w & 1;     // 2M x 2N wave grid
  const long bm = (long)blockIdx.y * 128, bn = (long)blockIdx.x * 128;
  const int NK = K >> 6;

  const int srl = lane >> 3;
  const int scE = ((lane & 7) ^ srl) * 8;
  const int c0 = (g ^ (q & 7)) * 8;
  const int c1 = c0 ^ 32;
  const int aB = (wgM * 64 + q) * 64;
  const int bB = (wgN * 64 + q) * 64;

  f32x4 acc[4][4] = {};
  short8 a[4][2], b[4][2];

#define STAGE(gp, gbase, jj, ldsOff) do {                                     \
    _Pragma("unroll")                                                         \
    for (int c_ = 0; c_ < 4; ++c_) {                                          \
      const long row_ = (c_ * 4 + w) * 8 + srl;                               \
      gload_lds16(&(gp)[((gbase) + row_) * (long)K + (jj) * 64 + scE],        \
                  &lds[(ldsOff) + (c_ * 4 + w) * 512]);                       \
    }                                                                         \
  } while (0)

#define QUADD(n0, n1)                                                         \
  do {                                                                        \
    __builtin_amdgcn_s_setprio(1);                                            \
    _Pragma("unroll")                                                         \
    for (int mi_ = 0; mi_ < 4; ++mi_) {                                       \
      acc[mi_][n0] = __builtin_amdgcn_mfma_f32_16x16x32_bf16(                 \
          a[mi_][0], b[n0][0], acc[mi_][n0], 0, 0, 0);                        \
      acc[mi_][n0] = __builtin_amdgcn_mfma_f32_16x16x32_bf16(                 \
          a[mi_][1], b[n0][1], acc[mi_][n0], 0, 0, 0);                        \
      acc[mi_][n1] = __builtin_amdgcn_mfma_f32_16x16x32_bf16(                 \
          a[mi_][0], b[n1][0], acc[mi_][n1], 0, 0, 0);                        \
      acc[mi_][n1] = __builtin_amdgcn_mfma_f32_16x16x32_bf16(                 \
          a[mi_][1], b[n1][1], acc[mi_][n1], 0, 0, 0);                        \
    }                                                                         \
    __builtin_amdgcn_s_setprio(0);                                            \
  } while (0)

  for (int j = 0; j < NK; ++j) {
    STAGE(A, bm, j, 0);
    STAGE(B, bn, j, 8192);
    VM0();                                  // tile landed
    BAR();                                  // all waves see full tile
#pragma unroll
    for (int mi = 0; mi < 4; ++mi) {
      a[mi][0] = *(const short8*)&lds[aB + mi * 1024 + c0];
      a[mi][1] = *(const short8*)&lds[aB + mi * 1024 + c1];
    }
#pragma unroll
    for (int ni = 0; ni < 4; ++ni) {
      b[ni][0] = *(const short8*)&lds[8192 + bB + ni * 1024 + c0];
      b[ni][1] = *(const short8*)&lds[8192 + bB + ni * 1024 + c1];
    }
    QUADD(0, 1);
    QUADD(2, 3);
    BAR();                                  // all reads done -> safe to restage
  }

#pragma unroll
  for (int ni = 0; ni < 4; ++ni) {
    const int col = (int)bn + wgN * 64 + ni * 16 + q;
    float bv;
    if (MODE == 4) {
      const int which = col >> 11, c = col & 2047;
      const float* bp = which == 0 ? b0 : (which == 1 ? b1 : b2);
      bv = bp[c];
    } else {
      bv = b0[col];
    }
#pragma unroll
    for (int mi = 0; mi < 4; ++mi)
#pragma unroll
      for (int r = 0; r < 4; ++r) {
        const long row = bm + wgM * 64 + mi * 16 + 4 * g + r;
        const float v = acc[mi][ni][r] + bv;
        if (MODE == 4) {
          const int which = col >> 11, c = col & 2047, head = c >> 7, d = c & 127;
          if (which == 0)      O0[((long)head * SEQ + row) * HD + d] = f2bu(v * QSCALE_L2E);
          else if (which == 1) O1[((long)head * SEQ + row) * HD + d] = f2bu(v);
          else                 O2[((long)head * HD + d) * SEQ + row] = f2bu(v);
        } else {
          Of[row * (long)N + col] = v;
        }
      }
  }
#undef STAGE
#undef QUADD
}

// ---------------- 64x128 bf16 GEMM  C = A[M,K] * B[N,K]^T + bias ------------
// Out-projection: dbuf 2-barrier structure. R28 proved single-buffer REGRESSES
// at this grid (512 blocks = 2 blocks/CU: no third block to hide the VM0
// drain). dbuf for 2-block/CU grids, single-buffer for >=3.
template<int MODE>
__global__ __launch_bounds__(256, 2) void gemm128(
    const unsigned short* __restrict__ A,
    const unsigned short* __restrict__ B,
    const float* __restrict__ b0, const float* __restrict__ b1, const float* __restrict__ b2,
    unsigned short* __restrict__ O0, unsigned short* __restrict__ O1, unsigned short* __restrict__ O2,
    float* __restrict__ Of, int M, int N, int K)
{
  constexpr int ASZ = 64 * 64;
  constexpr int BSZ = 128 * 64;

  extern __shared__ unsigned short lds[];
  const int tid = threadIdx.x;
  const int lane = tid & 63, w = tid >> 6;
  const int g = lane >> 4, q = lane & 15;
  const long bm = (long)blockIdx.y * 64, bn = (long)blockIdx.x * 128;
  const int NK = K >> 6;

  const int srl = lane >> 3;
  const int scE = ((lane & 7) ^ srl) * 8;
  const int c0 = (g ^ (q & 7)) * 8;
  const int c1 = c0 ^ 32;
  const int aB = q * 64;
  const int bB = (w * 32 + q) * 64;

  f32x4 acc[4][2] = {};
  short8 a[4][2], b[2][2];

#define STAGE_A(jj) do {                                                      \
    unsigned short* dst_ = lds + (((jj) & 1) ? ASZ : 0);                      \
    _Pragma("unroll")                                                         \
    for (int c_ = 0; c_ < 2; ++c_) {                                          \
      const long row_ = (c_ * 4 + w) * 8 + srl;                               \
      gload_lds16(&A[(bm + row_) * (long)K + (jj) * 64 + scE],                \
                  &dst_[(c_ * 4 + w) * 512]);                                 \
    }                                                                         \
  } while (0)

#define STAGE_B(jj) do {                                                      \
    unsigned short* dst_ = lds + 2 * ASZ + (((jj) & 1) ? BSZ : 0);            \
    _Pragma("unroll")                                                         \
    for (int c_ = 0; c_ < 4; ++c_) {                                          \
      const long row_ = (c_ * 4 + w) * 8 + srl;                               \
      gload_lds16(&B[(bn + row_) * (long)K + (jj) * 64 + scE],                \
                  &dst_[(c_ * 4 + w) * 512]);                                 \
    }                                                                         \
  } while (0)

#define QUAD8(ni)                                                             \
  do {                                                                        \
    __builtin_amdgcn_s_setprio(1);                                            \
    _Pragma("unroll")                                                         \
    for (int mi_ = 0; mi_ < 4; ++mi_) {                                       \
      acc[mi_][ni] = __builtin_amdgcn_mfma_f32_16x16x32_bf16(                 \
          a[mi_][0], b[ni][0], acc[mi_][ni], 0, 0, 0);                        \
      acc[mi_][ni] = __builtin_amdgcn_mfma_f32_16x16x32_bf16(                 \
          a[mi_][1], b[ni][1], acc[mi_][ni], 0, 0, 0);                        \
    }                                                                         \
    __builtin_amdgcn_s_setprio(0);                                            \
  } while (0)

  STAGE_A(0); STAGE_B(0);
  STAGE_A(1); STAGE_B(1);
  VM6();
  BAR();

  for (int j = 0; j < NK; ++j) {
    unsigned short* At = lds + ((j & 1) ? ASZ : 0);
    unsigned short* Bt = lds + 2 * ASZ + ((j & 1) ? BSZ : 0);

#pragma unroll
    for (int mi = 0; mi < 4; ++mi) {
      a[mi][0] = *(const short8*)&At[aB + mi * 1024 + c0];
      a[mi][1] = *(const short8*)&At[aB + mi * 1024 + c1];
    }
#pragma unroll
    for (int ni = 0; ni < 2; ++ni) {
      b[ni][0] = *(const short8*)&Bt[bB + ni * 1024 + c0];
      b[ni][1] = *(const short8*)&Bt[bB + ni * 1024 + c1];
    }
    QUAD8(0);
    LGKM0();
    BAR();                                  // (a)
    if (j + 2 < NK) { STAGE_A(j + 2); STAGE_B(j + 2); }
    QUAD8(1);
    if (j < NK - 2) { VM6(); } else { VM0(); }
    BAR();                                  // (b)
  }

#pragma unroll
  for (int ni = 0; ni < 2; ++ni) {
    const int col = (int)bn + w * 32 + ni * 16 + q;
    float bv;
    if (MODE == 4) {
      const int which = col >> 11, c = col & 2047;
      const float* bp = which == 0 ? b0 : (which == 1 ? b1 : b2);
      bv = bp[c];
    } else {
      bv = b0[col];
    }
#pragma unroll
    for (int mi = 0; mi < 4; ++mi)
#pragma unroll
      for (int r = 0; r < 4; ++r) {
        const long row = bm + mi * 16 + 4 * g + r;
        const float v = acc[mi][ni][r] + bv;
        if (MODE == 4) {
          const int which = col >> 11, c = col & 2047, head = c >> 7, d = c & 127;
          if (which == 0)      O0[((long)head * SEQ + row) * HD + d] = f2bu(v * QSCALE_L2E);
          else if (which == 1) O1[((long)head * SEQ + row) * HD + d] = f2bu(v);
          else                 O2[((long)head * HD + d) * SEQ + row] = f2bu(v);
        } else {
          Of[row * (long)N + col] = v;
        }
      }
  }
#undef STAGE_A
#undef STAGE_B
#undef QUAD8
}

// ---------------- flash attention v15: QK-ahead software pipeline -----------
// R26-verified WIN (66.0 -> 62.3us): base = R24 (gload_lds staging, K/V
// dbuf, Pt path, XCD decode). Per phase t:
//   STAGE_K(t+2)->Kbuf[t&1]; QK(t+1) MFMA chain; exp/pack/Pt/pf of tile t
//   (VALU under the QK MFMAs); PV(t); BAR; STAGE_V(t+2); vmcnt(4); BAR.
// R27's role-split waves REGRESSED (84us) -> this exact version is final.
#define KVB 64
__global__ __launch_bounds__(256) void flash_attn(
    const unsigned short* __restrict__ Qb,
    const unsigned short* __restrict__ Kb,
    const unsigned short* __restrict__ VTb,
    unsigned short* __restrict__ attnb)      // [SEQ][HID] bf16
{
  // S (elements): Kt0 @0 | Kt1 @8192 | Vt0 @16384 | Vt1 @24576 | Pt @32768
  extern __shared__ unsigned short S[];      // 36864 us = 72KB
  const int tid = threadIdx.x;
  const int l = tid & 63, w = tid >> 6;
  const int g = l >> 4, q = l & 15;
  const int bid = blockIdx.x;
  const int jj = bid >> 3;
  const int h = ((bid & 7) << 1) | (jj >> 5);   // 2 heads per XCD (R19-proven)
  const int qb = jj & 31;
  const int qrow0 = qb * 64 + w * 16;

  unsigned short* Pw = S + 32768 + w * 1024;

  short8 qf[4];
#pragma unroll
  for (int dc = 0; dc < 4; ++dc)
    qf[dc] = *(const short8*)&Qb[((long)h * SEQ + qrow0 + q) * HD + dc * 32 + g * 8];

  f32x4 oacc[8] = {};
  f32x4 saccA[4], saccB[4];
  const f32x4 zero4 = {};
  float lsum[4] = {0.f, 0.f, 0.f, 0.f};

  const unsigned short* Kg = Kb + (long)h * SEQ * HD;
  const unsigned short* Vg = VTb + (long)h * HD * SEQ;

  // R24-proven staging geometry (pre-swizzled global source, linear LDS dest)
  const int kce = ((l & 15) ^ (l >> 4)) * 8;        // K, even calls
  const int kco = kce ^ 32;                         // K, odd calls
  const int vce = ((l & 7) ^ ((l >> 3) & 7)) * 8;   // V, all calls
  const int krl = l >> 4;
  const int vrl = l >> 3;
  unsigned short* KdB = S + w * 2048;               // + buf*8192 + c*512
  unsigned short* VdB = S + 16384 + w * 2048;

#define STAGE_K(kb_, bufsel) do {                                             \
    const unsigned short* Kp_ = Kg + (long)((kb_) + w * 16 + krl) * HD;       \
    unsigned short* Kd_ = KdB + (bufsel) * 8192;                              \
    gload_lds16(Kp_ + 0 * 4 * HD + kce, Kd_ + 0 * 512);                       \
    gload_lds16(Kp_ + 1 * 4 * HD + kco, Kd_ + 1 * 512);                       \
    gload_lds16(Kp_ + 2 * 4 * HD + kce, Kd_ + 2 * 512);                       \
    gload_lds16(Kp_ + 3 * 4 * HD + kco, Kd_ + 3 * 512);                       \
  } while (0)

#define STAGE_V(kb_, bufsel) do {                                             \
    const unsigned short* Vp_ = Vg + (long)(w * 32 + vrl) * SEQ + (kb_) + vce;\
    unsigned short* Vd_ = VdB + (bufsel) * 8192;                              \
    gload_lds16(Vp_ + 0 * 8 * SEQ, Vd_ + 0 * 512);                            \
    gload_lds16(Vp_ + 1 * 8 * SEQ, Vd_ + 1 * 512);                            \
    gload_lds16(Vp_ + 2 * 8 * SEQ, Vd_ + 2 * 512);                            \
    gload_lds16(Vp_ + 3 * 8 * SEQ, Vd_ + 3 * 512);                            \
  } while (0)

#define QKT(T1, SN) do {                                                      \
    const unsigned short* Kt_ = S + ((T1) & 1) * 8192;                        \
    __builtin_amdgcn_s_setprio(1);                                            \
    _Pragma("unroll")                                                         \
    for (int kc = 0; kc < 4; ++kc) {                                          \
      const int krow_ = kc * 16 + q;                                          \
      const int sw_ = (krow_ & 7) << 4;                                       \
      _Pragma("unroll")                                                       \
      for (int dc = 0; dc < 4; ++dc) {                                        \
        short8 kf_ = *(const short8*)&Kt_[((krow_ * 256 + dc * 64 + g * 16) ^ sw_) >> 1]; \
        SN[kc] = __builtin_amdgcn_mfma_f32_16x16x32_bf16(qf[dc], kf_, SN[kc], 0, 0, 0);   \
      }                                                                       \
    }                                                                         \
    __builtin_amdgcn_s_setprio(0);                                            \
  } while (0)

#define FINISH_PV(T, SC) do {                                                 \
    float p_[4][4];                                                           \
    _Pragma("unroll")                                                         \
    for (int r = 0; r < 4; ++r) {                                             \
      _Pragma("unroll")                                                       \
      for (int kc = 0; kc < 4; ++kc) p_[kc][r] = exp2fast(SC[kc][r]);         \
      lsum[r] += (p_[0][r] + p_[1][r]) + (p_[2][r] + p_[3][r]);               \
    }                                                                         \
    _Pragma("unroll")                                                         \
    for (int r = 0; r < 4; ++r) {                                             \
      const int prow_ = 4 * g + r;                                            \
      const int sw_ = (prow_ & 7) << 4;                                       \
      _Pragma("unroll")                                                       \
      for (int kc = 0; kc < 4; ++kc)                                          \
        Pw[((prow_ * 128 + (kc * 16 + q) * 2) ^ sw_) >> 1] = f2bu_fast(p_[kc][r]); \
    }                                                                         \
    short8 pf_[2];                                                            \
    const int psw_ = (q & 7) << 4;                                            \
    _Pragma("unroll")                                                         \
    for (int ks = 0; ks < 2; ++ks)                                            \
      pf_[ks] = *(const short8*)&Pw[((q * 128 + ks * 64 + g * 16) ^ psw_) >> 1]; \
    const unsigned short* Vt_ = S + 16384 + ((T) & 1) * 8192;                 \
    __builtin_amdgcn_s_setprio(1);                                            \
    _Pragma("unroll")                                                         \
    for (int dt = 0; dt < 8; ++dt) {                                          \
      const int vrow_ = dt * 16 + q;                                          \
      _Pragma("unroll")                                                       \
      for (int ks = 0; ks < 2; ++ks) {                                        \
        short8 vf_ = *(const short8*)&Vt_[((vrow_ * 128 + ks * 64 + g * 16) ^ psw_) >> 1]; \
        oacc[dt] = __builtin_amdgcn_mfma_f32_16x16x32_bf16(pf_[ks], vf_, oacc[dt], 0, 0, 0); \
      }                                                                       \
    }                                                                         \
    __builtin_amdgcn_s_setprio(0);                                            \
  } while (0)

#define PHASE(T, SC, SN) do {                                                 \
    if ((T) + 2 < 32) STAGE_K(((T) + 2) * KVB, (T) & 1);                      \
    if ((T) + 1 < 32) {                                                       \
      _Pragma("unroll")                                                       \
      for (int kc = 0; kc < 4; ++kc) SN[kc] = zero4;                          \
      QKT((T) + 1, SN);                                                       \
    }                                                                         \
    FINISH_PV(T, SC);                                                         \
    BAR();                                                                    \
    if ((T) + 2 < 32) STAGE_V(((T) + 2) * KVB, (T) & 1);                      \
    if ((T) <= 29) { VM4(); } else { VM0(); }                                 \
    BAR();                                                                    \
  } while (0)

  // ---- prologue: tiles 0,1 staged; QK(0) computed; barrier so no wave
  // overwrites Kbuf0 (phase 0's STAGE_K(2)) before all waves read it.
  STAGE_K(0, 0); STAGE_V(0, 0);
  STAGE_K(KVB, 1); STAGE_V(KVB, 1);
  VM0();
  BAR();
#pragma unroll
  for (int kc = 0; kc < 4; ++kc) saccA[kc] = zero4;
  QKT(0, saccA);
  BAR();

  for (int t = 0; t < 32; t += 2) {
    PHASE(t, saccA, saccB);
    PHASE(t + 1, saccB, saccA);
  }

  // sum exp over the 16 q-lanes (KV columns live on q within each 16-lane grp)
#pragma unroll
  for (int off = 1; off < 16; off <<= 1)
#pragma unroll
    for (int r = 0; r < 4; ++r) lsum[r] += __shfl_xor(lsum[r], off);

  const float rl0 = 1.f / lsum[0], rl1 = 1.f / lsum[1];
  const float rl2 = 1.f / lsum[2], rl3 = 1.f / lsum[3];
#pragma unroll
  for (int dt = 0; dt < 8; ++dt) {
    const long colb = (long)h * HD + dt * 16 + q;
    attnb[(long)(qrow0 + 4 * g + 0) * HID + colb] = f2bu(oacc[dt][0] * rl0);
    attnb[(long)(qrow0 + 4 * g + 1) * HID + colb] = f2bu(oacc[dt][1] * rl1);
    attnb[(long)(qrow0 + 4 * g + 2) * HID + colb] = f2bu(oacc[dt][2] * rl2);
    attnb[(long)(qrow0 + 4 * g + 3) * HID + colb] = f2bu(oacc[dt][3] * rl3);
  }
#undef STAGE_K
#undef STAGE_V
#undef QKT
#undef FINISH_PV
#undef PHASE
}

extern "C" void kernel_launch(void* const* d_in, const int* in_sizes, int n_in,
                              void* d_out, int out_size, void* d_ws, size_t ws_size,
                              hipStream_t stream)
{
  const float* x  = (const float*)d_in[0];
  const float* wq = (const float*)d_in[1];
  const float* bq = (const float*)d_in[2];
  const float* wk = (const float*)d_in[3];
  const float* bk = (const float*)d_in[4];
  const float* wv = (const float*)d_in[5];
  const float* bv = (const float*)d_in[6];
  const float* wo = (const float*)d_in[7];
  const float* bo = (const float*)d_in[8];

  const long NEL = (long)HID * HID;
  unsigned short* Xb   = (unsigned short*)d_ws;
  unsigned short* Wqkv = Xb + NEL;
  unsigned short* Wob  = Wqkv + 3 * NEL;
  unsigned short* Qbuf = Wob + NEL;
  unsigned short* Kbuf = Qbuf + NEL;
  unsigned short* VTb  = Kbuf + NEL;
  unsigned short* Attn = VTb + NEL;

  // one-time opt-in for 72KB dynamic LDS (host-side, graph-capture safe)
  static bool attrDone = false;
  if (!attrDone) {
    hipFuncSetAttribute(reinterpret_cast<const void*>(flash_attn),
                        hipFuncAttributeMaxDynamicSharedMemorySize, 73728);
    attrDone = true;
  }

  cvt_kernel<<<dim3(512, 5), 256, 0, stream>>>(
      x, wq, wk, wv, wo, Xb, Wqkv, Wqkv + NEL, Wqkv + 2 * NEL, Wob, (int)NEL);

  gemm97<4><<<dim3(48, 16), 256, 32768, stream>>>(
      Xb, Wqkv, bq, bk, bv, Qbuf, Kbuf, VTb, nullptr, SEQ, 3 * HID, HID);

  flash_attn<<<dim3(512), 256, 73728, stream>>>(Qbuf, Kbuf, VTb, Attn);

  gemm128<3><<<dim3(16, 32), 256, 49152, stream>>>(
      Attn, Wob, bo, nullptr, nullptr, nullptr, nullptr, nullptr,
      (float*)d_out, SEQ, HID, HID);
}